// Round 1
// baseline (153.657 us; speedup 1.0000x reference)
//
#include <hip/hip_runtime.h>

typedef unsigned short u16;
typedef unsigned int   u32;
typedef unsigned long long u64;
typedef long long i64;

constexpr int DOF    = 300000;
constexpr int NB     = 8;
constexpr int NFIX   = 3000;
constexpr int NEWTON = 6;

// ---- cooperative config: 240 blocks x 512 thr x 20 elem = 1 block/CU ----
constexpr int CTPB  = 512;
constexpr int CEPT  = 20;
constexpr int CEPB  = CTPB * CEPT;                 // 10240
constexpr int CNBX  = (DOF + CEPB - 1) / CEPB;     // 30 blocks per batch
constexpr int CGRID = CNBX * NB;                   // 240
constexpr int NLINES = NEWTON * NB * 6;            // 288 acc lines per bank

// ---- fallback config (proven multi-kernel shape) ----
constexpr int FTPB  = 256;
constexpr int FEPT  = 16;
constexpr int FEPB  = FTPB * FEPT;                 // 4096
constexpr int FNBX  = (DOF + FEPB - 1) / FEPB;     // 74
constexpr int FGRID = FNBX * NB;                   // 592

// ---- static device scratch (no d_ws dependence; .bss zero-init) ----
__device__ float g_part[NEWTON][NB][FNBX][8];      // fallback only
__device__ float g_UW[NB * DOF];                   // fallback only

// acc line: u64, top byte = arrival count, low 56 = biased fixed-point sum
// (scale 2^20, per-add bias 2^44; 30 adds: bias 30*2^44, |sum| << 2^56).
// Count byte == CNBX is itself the publication: pollers read lines directly
// (no separate pub hop). Two banks: g_acc = speculative (alpha=1) rounds,
// g_facc = exact synced fallback rounds. Parity-banked across calls; the
// current call's banks were zeroed by the previous call (stream-serialized).
struct alignas(64) PadU64 { u64 v; u64 pad[7]; };
__device__ PadU64 g_acc [2][NEWTON][NB][6];
__device__ PadU64 g_facc[2][NEWTON][NB][6];
__device__ PadU64 g_done[2];                       // parity-banked finish count
__device__ u32    g_call;                          // bumped after ALL blocks done

constexpr u64   CNT_ONE  = 1ull << 56;
constexpr u64   SUM_MASK = CNT_ONE - 1ull;
constexpr i64   ABIAS    = 1ll << 44;
constexpr float FXS      = 1048576.0f;             // 2^20
constexpr float FXS_INV  = 9.5367431640625e-07f;   // 2^-20

__device__ __forceinline__ u16 f2b(float f) {      // f32 -> bf16 RNE
  u32 x = __float_as_uint(f);
  u32 r = x + 0x7fffu + ((x >> 16) & 1u);
  return (u16)(r >> 16);
}

// NaN-safe clamp + fixed-point encode. Clamp at 8e6 (q <= 8.39e12 < 2^43)
// never binds on the normal path (block partials ~1e4); it only matters if
// the speculative trajectory diverges, where it keeps the count byte clean
// (no carry into bits 56+) so verification still terminates and the bad
// round is detected via the alpha pick. NaN fails the first compare -> -8e6
// -> finite garbage -> verdict mismatch -> fallback.
__device__ __forceinline__ u64 enc_sum(float s) {
  float sa = s;
  if (!(sa > -8.0e6f)) sa = -8.0e6f;
  if (sa > 8.0e6f)     sa = 8.0e6f;
  return (u64)((i64)(sa * FXS) + ABIAS);
}

// Spin until line's arrival count == CNBX, then decode the exact global sum.
// All pollers read the same final 64-bit value -> identical float -> the
// alpha decision is deterministic and grid-uniform.
template<int SLP>
__device__ __forceinline__ float poll_line(u64* p) {
  u64 v = __hip_atomic_load(p, __ATOMIC_RELAXED, __HIP_MEMORY_SCOPE_AGENT);
  while ((v >> 56) != (u64)CNBX) {
    __builtin_amdgcn_s_sleep(SLP);
    v = __hip_atomic_load(p, __ATOMIC_RELAXED, __HIP_MEMORY_SCOPE_AGENT);
  }
  return (float)((i64)(v & SUM_MASK) - (i64)CNBX * ABIAS) * FXS_INV;
}

// ---- 20-elem vector load/store (coop path). f32: 5x float4 (80B-aligned);
// bf16: 5x uint2 (40B offsets are 8B-aligned). ----
template<bool BF>
__device__ __forceinline__ void load20(const void* p, long long off, float* dst) {
  if (BF) {
    const u16* b = (const u16*)p + off;
#pragma unroll
    for (int i = 0; i < 5; ++i) {
      uint2 a = *(const uint2*)(b + 4*i);
      u32 w0 = a.x, w1 = a.y;
      dst[4*i]   = __uint_as_float((w0 & 0xffffu) << 16);
      dst[4*i+1] = __uint_as_float(w0 & 0xffff0000u);
      dst[4*i+2] = __uint_as_float((w1 & 0xffffu) << 16);
      dst[4*i+3] = __uint_as_float(w1 & 0xffff0000u);
    }
  } else {
    const float* b = (const float*)p + off;
#pragma unroll
    for (int i = 0; i < 5; ++i) {
      float4 v = *(const float4*)(b + 4*i);
      dst[4*i] = v.x; dst[4*i+1] = v.y; dst[4*i+2] = v.z; dst[4*i+3] = v.w;
    }
  }
}

template<bool BF>
__device__ __forceinline__ void store20(void* p, long long off, const float* src) {
  if (BF) {
    u16* b = (u16*)p + off;
#pragma unroll
    for (int i = 0; i < 5; ++i) {
      u32 w0 = (u32)f2b(src[4*i])   | ((u32)f2b(src[4*i+1]) << 16);
      u32 w1 = (u32)f2b(src[4*i+2]) | ((u32)f2b(src[4*i+3]) << 16);
      *(uint2*)(b + 4*i) = make_uint2(w0, w1);
    }
  } else {
    float* b = (float*)p + off;
#pragma unroll
    for (int i = 0; i < 5; ++i)
      *(float4*)(b + 4*i) = make_float4(src[4*i], src[4*i+1], src[4*i+2], src[4*i+3]);
  }
}

// 16-elem versions (fallback path)
template<bool BF>
__device__ __forceinline__ void load16(const void* p, long long off, float* dst) {
  if (BF) {
    const u16* b = (const u16*)p + off;
    uint4 a0 = *(const uint4*)(b);
    uint4 a1 = *(const uint4*)(b + 8);
    u32 w[8] = {a0.x, a0.y, a0.z, a0.w, a1.x, a1.y, a1.z, a1.w};
#pragma unroll
    for (int i = 0; i < 8; ++i) {
      dst[2*i]   = __uint_as_float((w[i] & 0xffffu) << 16);
      dst[2*i+1] = __uint_as_float(w[i] & 0xffff0000u);
    }
  } else {
    const float* b = (const float*)p + off;
#pragma unroll
    for (int i = 0; i < 4; ++i) {
      float4 v = *(const float4*)(b + 4*i);
      dst[4*i] = v.x; dst[4*i+1] = v.y; dst[4*i+2] = v.z; dst[4*i+3] = v.w;
    }
  }
}

template<bool BF>
__device__ __forceinline__ void store16(void* p, long long off, const float* src) {
  if (BF) {
    u16* b = (u16*)p + off;
    u32 w[8];
#pragma unroll
    for (int i = 0; i < 8; ++i)
      w[i] = (u32)f2b(src[2*i]) | ((u32)f2b(src[2*i+1]) << 16);
    *(uint4*)(b)     = make_uint4(w[0], w[1], w[2], w[3]);
    *(uint4*)(b + 8) = make_uint4(w[4], w[5], w[6], w[7]);
  } else {
    float* b = (float*)p + off;
#pragma unroll
    for (int i = 0; i < 4; ++i)
      *(float4*)(b + 4*i) = make_float4(src[4*i], src[4*i+1], src[4*i+2], src[4*i+3]);
  }
}

// dtype probe: k_diag in [1,2). bf16 -> every u16 in [0x3F80,0x4000]; f32 even
// words are random mantissa halves (false-positive p ~ 2e-22 over 8 words).
__device__ __forceinline__ bool probe_bf(const void* KD) {
  const u16* k = (const u16*)KD;
  bool bf = true;
#pragma unroll
  for (int i = 0; i < 8; ++i) {
    u16 v = k[2*i];
    bf = bf && (v >= 0x3F80u && v <= 0x4000u);
  }
  return bf;
}

// Gram-form partials (NE elems/thread): cr(a) = filt*(1+a) - P*a^2 - Q*a^3,
// P=1.2*u*d^2, Q=0.4*d^3, d = -filt/den (exact cubic since den*d = -filt).
// sum cr(a)^2 is a quadratic form in (filt,P,Q) -> 6 sums cover init-norm^2
// and all 6 trial norms. Fixed dofs: filt=0 -> d=P=Q=0.
template<int NE>
__device__ __forceinline__ void compute_gram(bool act, const float* u,
                                             const float* f, const float* kv,
                                             float* du, u32 mbits, float* G) {
#pragma unroll
  for (int j = 0; j < 6; ++j) G[j] = 0.0f;
  if (!act) {
#pragma unroll
    for (int e = 0; e < NE; ++e) du[e] = 0.0f;
    return;
  }
#pragma unroll
  for (int e = 0; e < NE; ++e) {
    const bool fr = ((mbits >> e) & 1u) == 0u;
    const float uu = u[e], ff = f[e], kk = kv[e];
    const float u2 = uu * uu;
    const float g    = fmaf(0.4f * u2, uu, kk * uu);
    const float filt = fr ? (ff - g) : 0.0f;
    const float den  = fmaf(1.2f, u2, kk);
    const float d    = -filt * __builtin_amdgcn_rcpf(den);
    du[e] = d;
    const float d2 = d * d;
    const float P  = (1.2f * uu) * d2;
    const float Q  = (0.4f * d2) * d;
    G[0] = fmaf(filt, filt, G[0]);
    G[1] = fmaf(filt, P,    G[1]);
    G[2] = fmaf(filt, Q,    G[2]);
    G[3] = fmaf(P,    P,    G[3]);
    G[4] = fmaf(P,    Q,    G[4]);
    G[5] = fmaf(Q,    Q,    G[5]);
  }
}

// alpha pick from 6 Gram sums (compare squared; fallback idx 5 == 0.05)
__device__ __forceinline__ int pick_idx(const float* G) {
  const float AL[6] = {1.0f, 0.5f, 0.25f, 0.125f, 0.0625f, 0.05f};
  int idx = 5;
  bool found = false;
#pragma unroll
  for (int t = 0; t < 6; ++t) {
    const float a = AL[t], s = 1.0f + a, a2 = a * a;
    const float n2 = s * s * G[0] - 2.0f * s * a2 * G[1] - 2.0f * s * a2 * a * G[2]
                   + a2 * a2 * G[3] + 2.0f * a2 * a2 * a * G[4]
                   + a2 * a2 * a2 * G[5];
    if (!found && n2 < G[0]) { idx = t; found = true; }
  }
  return idx;
}

// ================= cooperative single-dispatch path =================
// Speculate-then-verify: the line search on this problem picks alpha=1.0
// every round (Newton on a diagonally-dominant SPD system with mild cubic;
// iter-0 expected norm^2 ratio ~0.47 with ~60-sigma concentration margin,
// quadratic contraction after). Phase 1 runs all NEWTON rounds back-to-back
// with alpha=1 and NO waits, streaming each round's 6 Gram sums into the
// arrival-counted lines (fetch_add result discarded). OUT is stored
// speculatively, then ONE verification wait checks all 36 global sums: if
// every round's pick_idx == 0 the speculation was exact (same fp ops as the
// synced path) and we're done. Otherwise all blocks (deterministic verdict:
// identical integers) reload u0 and rerun the proven synced loop against the
// second accumulator bank.
__global__ void __launch_bounds__(CTPB, 2) k_coop(const void* __restrict__ F,
                                                  const void* __restrict__ U0,
                                                  const void* __restrict__ KD,
                                                  const int* __restrict__ FIX,
                                                  void* __restrict__ OUT) {
  const int tid = threadIdx.x, bid = blockIdx.x;
  const int b = bid / CNBX, bx = bid - b * CNBX;
  const int d0 = bx * CEPB + tid * CEPT;
  const bool act = (d0 + CEPT <= DOF);      // threads are full-vec or inactive
  const long long gb = (long long)b * DOF + d0;
  const bool bf = probe_bf(KD);
  const float ALTAB[6] = {1.0f, 0.5f, 0.25f, 0.125f, 0.0625f, 0.05f};

  __shared__ u32   mw[CEPB / 32 + 1];       // +1 pad word for 20-bit extraction
  __shared__ float sred[CTPB / 64][8];
  __shared__ float sG[NEWTON * 6];          // verified global sums
  __shared__ float gG[6];                   // fallback per-round sums
  __shared__ u32   sflag;

  // parity select; previous call fully retired (stream-serialized), so its
  // g_call bump is visible via the dispatch boundary.
  const u32 call = __hip_atomic_load(&g_call, __ATOMIC_RELAXED,
                                     __HIP_MEMORY_SCOPE_AGENT);
  const int par  = (int)(call & 1u);

  // prefetch inputs first: overlap HBM latency with resets + mask build
  float u[CEPT], f[CEPT], kv[CEPT], du[CEPT];
  if (act) {
    if (bf) { load20<true >(U0, gb, u); load20<true >(F, gb, f); load20<true >(KD, d0, kv); }
    else    { load20<false>(U0, gb, u); load20<false>(F, gb, f); load20<false>(KD, d0, kv); }
  }

  // zero the OTHER parity's banks (their last user, call-1, fully retired):
  // 2*288 lines across 240 blocks = <=3 stores per block, off critical path.
  if (tid == 0) {
    for (int L = bid; L < 2 * NLINES; L += CGRID) {
      const int s  = L / NLINES;
      const int r  = L % NLINES;
      const int n2 = r / (NB * 6), rr = r % (NB * 6);
      u64* p = s ? &g_facc[par ^ 1][n2][rr / 6][rr % 6].v
                 : &g_acc [par ^ 1][n2][rr / 6][rr % 6].v;
      __hip_atomic_store(p, 0ull, __ATOMIC_RELAXED, __HIP_MEMORY_SCOPE_AGENT);
    }
    if (bid == 0)
      __hip_atomic_store(&g_done[par ^ 1].v, 0ull,
                         __ATOMIC_RELAXED, __HIP_MEMORY_SCOPE_AGENT);
  }

  // block-local fixed-dof bitmask over this block's 10240-dof window
  for (int i = tid; i < CEPB / 32 + 1; i += CTPB) mw[i] = 0u;
  __syncthreads();
  const int blk_base = bx * CEPB;
  for (int i = tid; i < NFIX; i += CTPB) {
    const int d = FIX[i] - blk_base;
    if (d >= 0 && d < CEPB) atomicOr(&mw[d >> 5], 1u << (d & 31));
  }
  __syncthreads();
  const int off = tid * CEPT;                // 20 bits, may span 2 words
  const u64 mm = (((u64)mw[(off >> 5) + 1] << 32) | (u64)mw[off >> 5]) >> (off & 31);
  const u32 mbits = (u32)mm & 0xFFFFFu;

  // ---------------- phase 1: alpha=1 trajectory, zero waits ----------------
  for (int n = 0; n < NEWTON; ++n) {
    float G[6];
    compute_gram<CEPT>(act, u, f, kv, du, mbits, G);
    { // 8-wave block reduce into sred[*][j]
      const int lane = tid & 63, wid = tid >> 6;
#pragma unroll
      for (int j = 0; j < 6; ++j) {
        float v = G[j];
#pragma unroll
        for (int o = 32; o > 0; o >>= 1) v += __shfl_down(v, o, 64);
        if (lane == 0) sred[wid][j] = v;
      }
      __syncthreads();
    }
    if (tid < 6) {                           // fire-and-forget arrival+sum
      float s = sred[0][tid];
#pragma unroll
      for (int w2 = 1; w2 < CTPB / 64; ++w2) s += sred[w2][tid];
      (void)__hip_atomic_fetch_add(&g_acc[par][n][b][tid].v,
                                   CNT_ONE | enc_sum(s), __ATOMIC_RELAXED,
                                   __HIP_MEMORY_SCOPE_AGENT);
    }
    __syncthreads();                         // sred WAR vs next round
    if (act) {
#pragma unroll
      for (int e = 0; e < CEPT; ++e) u[e] = fmaf(1.0f, du[e], u[e]);
    }
  }

  // speculative store: overlaps the verification wait; fallback overwrites.
  if (act) {
    if (bf) store20<true >(OUT, gb, u);
    else    store20<false>(OUT, gb, u);
  }

  // ---------------- single verification wait ----------------
  if (tid < NEWTON * 6) {
    const int n = tid / 6, j = tid - n * 6;
    sG[tid] = poll_line<2>(&g_acc[par][n][b][j].v);
  }
  __syncthreads();
  if (tid == 0) {
    u32 ok = 1u;
#pragma unroll
    for (int n = 0; n < NEWTON; ++n) ok &= (pick_idx(&sG[6 * n]) == 0) ? 1u : 0u;
    sflag = ok;
  }
  __syncthreads();

  if (!sflag) {
    // ------------- fallback: exact synced loop (rare path) -------------
    if (act) {
      if (bf) load20<true >(U0, gb, u);
      else    load20<false>(U0, gb, u);
    }
    for (int n = 0; n < NEWTON; ++n) {
      float G[6];
      compute_gram<CEPT>(act, u, f, kv, du, mbits, G);
      {
        const int lane = tid & 63, wid = tid >> 6;
#pragma unroll
        for (int j = 0; j < 6; ++j) {
          float v = G[j];
#pragma unroll
          for (int o = 32; o > 0; o >>= 1) v += __shfl_down(v, o, 64);
          if (lane == 0) sred[wid][j] = v;
        }
        __syncthreads();
      }
      if (tid < 6) {
        float s = sred[0][tid];
#pragma unroll
        for (int w2 = 1; w2 < CTPB / 64; ++w2) s += sred[w2][tid];
        (void)__hip_atomic_fetch_add(&g_facc[par][n][b][tid].v,
                                     CNT_ONE | enc_sum(s), __ATOMIC_RELAXED,
                                     __HIP_MEMORY_SCOPE_AGENT);
        gG[tid] = poll_line<8>(&g_facc[par][n][b][tid].v);   // direct-line poll
      }
      __syncthreads();
      float GG[6];
#pragma unroll
      for (int j = 0; j < 6; ++j) GG[j] = gG[j];
      const float ab = ALTAB[pick_idx(GG)];
      if (act) {
#pragma unroll
        for (int e = 0; e < CEPT; ++e) u[e] = fmaf(ab, du[e], u[e]);
      }
      __syncthreads();                       // sred/gG WAR vs next round
    }
    if (act) {
      if (bf) store20<true >(OUT, gb, u);
      else    store20<false>(OUT, gb, u);
    }
  }

  // g_call bump gated on ALL 240 blocks finishing.
  if (tid == 0) {
    const u64 old = __hip_atomic_fetch_add(&g_done[par].v, 1ull,
                                           __ATOMIC_RELAXED,
                                           __HIP_MEMORY_SCOPE_AGENT);
    if (old == (u64)(CGRID - 1))
      __hip_atomic_store(&g_call, call + 1u, __ATOMIC_RELAXED,
                         __HIP_MEMORY_SCOPE_AGENT);
  }
}

// ============ fallback multi-kernel path (proven 256/16/74 shape) ============
__device__ __forceinline__ u32 build_mask_fb(const int* __restrict__ FIX,
                                             int blk_base, int tid, u32* mw) {
  for (int i = tid; i < FEPB / 32; i += FTPB) mw[i] = 0u;
  __syncthreads();
  for (int i = tid; i < NFIX; i += FTPB) {
    const int d = FIX[i] - blk_base;
    if (d >= 0 && d < FEPB) atomicOr(&mw[d >> 5], 1u << (d & 31));
  }
  __syncthreads();
  const int off = tid * FEPT;
  return (mw[off >> 5] >> (off & 31)) & 0xFFFFu;
}

__device__ __forceinline__ void compute_partials7(bool act, const float* u,
                                                  const float* f, const float* kv,
                                                  float* du, u32 mbits, float* part) {
#pragma unroll
  for (int j = 0; j < 7; ++j) part[j] = 0.0f;
  const float AL[6] = {1.0f, 0.5f, 0.25f, 0.125f, 0.0625f, 0.05f};
  if (!act) {
#pragma unroll
    for (int e = 0; e < FEPT; ++e) du[e] = 0.0f;
    return;
  }
#pragma unroll
  for (int e = 0; e < FEPT; ++e) {
    const bool fr = ((mbits >> e) & 1u) == 0u;
    const float uu = u[e], ff = f[e], kk = kv[e];
    const float u2 = uu * uu;
    const float g    = fmaf(0.4f * u2, uu, kk * uu);
    const float filt = fr ? (ff - g) : 0.0f;
    part[0] = fmaf(filt, filt, part[0]);
    const float den = fmaf(1.2f, u2, kk);
    const float d   = -filt * __builtin_amdgcn_rcpf(den);
    du[e] = d;
    const float d2  = d * d;
    const float Bc  = 1.2f * uu * d2;
    const float Cc  = 0.4f * d2 * d;
#pragma unroll
    for (int t = 0; t < 6; ++t) {
      const float a  = AL[t];
      const float cr = fmaf(a, fmaf(a, fmaf(-Cc, a, -Bc), filt), filt);
      part[1 + t] = fmaf(cr, cr, part[1 + t]);
    }
  }
}

__device__ __forceinline__ float sum_pick_fb(float (*red)[8], int n, int b, int tid) {
  if (tid < FNBX) {
#pragma unroll
    for (int j = 0; j < 7; ++j)
      red[tid][j] = __hip_atomic_load(&g_part[n][b][tid][j], __ATOMIC_RELAXED,
                                      __HIP_MEMORY_SCOPE_AGENT);
  }
  __syncthreads();
#pragma unroll
  for (int s = 64; s >= 1; s >>= 1) {
    if (tid < s && tid + s < FNBX) {
#pragma unroll
      for (int j = 0; j < 7; ++j) red[tid][j] += red[tid + s][j];
    }
    __syncthreads();
  }
  const float initn = sqrtf(red[0][0]);
  const float AL[6] = {1.0f, 0.5f, 0.25f, 0.125f, 0.0625f, 0.05f};
  float ab = 0.05f;
  bool found = false;
#pragma unroll
  for (int t = 0; t < 6; ++t) {
    const float nt = sqrtf(red[0][1 + t]);
    if (!found && nt < initn) { ab = AL[t]; found = true; }
  }
  __syncthreads();
  return ab;
}

template<bool BF>
__device__ __forceinline__ void load_state_fb(const void* U0, const void* F,
                                              const void* KD, int n, long long gb,
                                              int d0, float* u, float* f, float* kv) {
  if (n == 0) load16<BF>(U0, gb, u);
  else {
#pragma unroll
    for (int i = 0; i < 4; ++i) {
      float4 q = *(const float4*)(g_UW + gb + 4*i);
      u[4*i] = q.x; u[4*i+1] = q.y; u[4*i+2] = q.z; u[4*i+3] = q.w;
    }
  }
  load16<BF>(F, gb, f);
  load16<BF>(KD, d0, kv);
}

__global__ void __launch_bounds__(FTPB) k_part_fb(const void* __restrict__ F,
                                                  const void* __restrict__ U0,
                                                  const void* __restrict__ KD,
                                                  const int* __restrict__ FIX, int n) {
  const int tid = threadIdx.x, bid = blockIdx.x;
  const int b = bid / FNBX, bx = bid - b * FNBX;
  const int d0 = bx * FEPB + tid * FEPT;
  const bool act = (d0 < DOF);
  const long long gb = (long long)b * DOF + d0;
  const bool bf = probe_bf(KD);
  __shared__ u32   mw[FEPB / 32];
  __shared__ float sred[FTPB / 64][8];
  const u32 mbits = build_mask_fb(FIX, bx * FEPB, tid, mw);
  float u[FEPT], f[FEPT], kv[FEPT], du[FEPT];
  if (act) {
    if (bf) load_state_fb<true >(U0, F, KD, n, gb, d0, u, f, kv);
    else    load_state_fb<false>(U0, F, KD, n, gb, d0, u, f, kv);
  }
  float part[7];
  compute_partials7(act, u, f, kv, du, mbits, part);
  const int lane = tid & 63, wid = tid >> 6;
#pragma unroll
  for (int j = 0; j < 7; ++j) {
    float v = part[j];
#pragma unroll
    for (int o = 32; o > 0; o >>= 1) v += __shfl_down(v, o, 64);
    if (lane == 0) sred[wid][j] = v;
  }
  __syncthreads();
  if (tid < 7)
    g_part[n][b][bx][tid] = sred[0][tid] + sred[1][tid] + sred[2][tid] + sred[3][tid];
}

__global__ void __launch_bounds__(FTPB) k_upd_fb(const void* __restrict__ F,
                                                 const void* __restrict__ U0,
                                                 const void* __restrict__ KD,
                                                 const int* __restrict__ FIX,
                                                 void* __restrict__ OUT, int n, int last) {
  const int tid = threadIdx.x, bid = blockIdx.x;
  const int b = bid / FNBX, bx = bid - b * FNBX;
  const int d0 = bx * FEPB + tid * FEPT;
  const bool act = (d0 < DOF);
  const long long gb = (long long)b * DOF + d0;
  const bool bf = probe_bf(KD);
  __shared__ u32   mw[FEPB / 32];
  __shared__ float red[80][8];
  const u32 mbits = build_mask_fb(FIX, bx * FEPB, tid, mw);
  const float ab = sum_pick_fb(red, n, b, tid);
  if (!act) return;
  float u[FEPT], f[FEPT], kv[FEPT], du[FEPT];
  if (bf) load_state_fb<true >(U0, F, KD, n, gb, d0, u, f, kv);
  else    load_state_fb<false>(U0, F, KD, n, gb, d0, u, f, kv);
  float part[7];
  compute_partials7(act, u, f, kv, du, mbits, part);   // recompute du
#pragma unroll
  for (int e = 0; e < FEPT; ++e) u[e] = fmaf(ab, du[e], u[e]);
#pragma unroll
  for (int i = 0; i < 4; ++i)
    *(float4*)(g_UW + gb + 4*i) = make_float4(u[4*i], u[4*i+1], u[4*i+2], u[4*i+3]);
  if (last) {
    if (bf) store16<true >(OUT, gb, u);
    else    store16<false>(OUT, gb, u);
  }
}

extern "C" void kernel_launch(void* const* d_in, const int* in_sizes, int n_in,
                              void* d_out, int out_size, void* d_ws, size_t ws_size,
                              hipStream_t stream) {
  const void* F   = d_in[0];               // external_forces [B, DOF]
  const void* U0  = d_in[1];               // u0              [B, DOF]
  const void* KD  = d_in[2];               // k_diag          [DOF]
  const int*  FIX = (const int*)d_in[3];   // fixed_dofs      [NFIX] int32
  void* OUT = d_out;

  void* args[] = {(void*)&F, (void*)&U0, (void*)&KD, (void*)&FIX, (void*)&OUT};
  hipError_t e = hipLaunchCooperativeKernel((void*)k_coop, dim3(CGRID), dim3(CTPB),
                                            args, 0, stream);
  if (e != hipSuccess) {
    (void)hipGetLastError();               // clear sticky error, take fallback
    for (int n = 0; n < NEWTON; ++n) {
      k_part_fb<<<FGRID, FTPB, 0, stream>>>(F, U0, KD, FIX, n);
      k_upd_fb<<<FGRID, FTPB, 0, stream>>>(F, U0, KD, FIX, d_out, n,
                                           (n == NEWTON - 1) ? 1 : 0);
    }
  }
}

// Round 2
// 123.599 us; speedup vs baseline: 1.2432x; 1.2432x over previous
//
#include <hip/hip_runtime.h>

typedef unsigned short u16;
typedef unsigned int   u32;
typedef unsigned long long u64;
typedef long long i64;

constexpr int DOF    = 300000;
constexpr int NB     = 8;
constexpr int NFIX   = 3000;
constexpr int NEWTON = 6;

// ---- cooperative config: 240 blocks x 512 thr x 20 elem = 1 block/CU ----
constexpr int CTPB  = 512;
constexpr int CEPT  = 20;
constexpr int CEPB  = CTPB * CEPT;                 // 10240
constexpr int CNBX  = (DOF + CEPB - 1) / CEPB;     // 30 blocks per batch
constexpr int CGRID = CNBX * NB;                   // 240
constexpr int NLINES = NEWTON * NB * 6;            // 288 acc lines per bank

// Speculated line-search outcome. The reference solves A*du = -filtered
// (du = -H^-1 r, the ASCENT direction): post-step residual is exactly
// cr(a) = filt*(1+a) - P a^2 - Q a^3, and n2(a)-G0 = (2a+a^2)G0
// - 2(1+a)a^2 G1 - 2(1+a)a^3 G2 + ... with G2 < 0 (~ -0.45 G0) and G1 <= 0,
// so NO trial alpha ever reduces the norm -> any_imp=False -> alpha=ALPHA_MIN
// =0.05 (pick_idx==5) every round. Round-1 HW evidence: speculating pick==0
// failed verification on every call (fallback signature in counters).
constexpr int   SPEC_PICK  = 5;
constexpr float SPEC_ALPHA = 0.05f;

// ---- fallback config (proven multi-kernel shape) ----
constexpr int FTPB  = 256;
constexpr int FEPT  = 16;
constexpr int FEPB  = FTPB * FEPT;                 // 4096
constexpr int FNBX  = (DOF + FEPB - 1) / FEPB;     // 74
constexpr int FGRID = FNBX * NB;                   // 592

// ---- static device scratch (no d_ws dependence; .bss zero-init) ----
__device__ float g_part[NEWTON][NB][FNBX][8];      // fallback only
__device__ float g_UW[NB * DOF];                   // fallback only

// acc line: u64, top byte = arrival count, low 56 = biased fixed-point sum
// (scale 2^20, per-add bias 2^44; 30 adds: bias 30*2^44, |sum| << 2^56).
// Count byte == CNBX is itself the publication: pollers read lines directly.
// Two banks: g_acc = speculative rounds, g_facc = exact synced fallback
// rounds. Parity-banked across calls; the current call's banks were zeroed
// by the previous call (stream-serialized).
struct alignas(64) PadU64 { u64 v; u64 pad[7]; };
__device__ PadU64 g_acc [2][NEWTON][NB][6];
__device__ PadU64 g_facc[2][NEWTON][NB][6];
__device__ PadU64 g_done[2];                       // parity-banked finish count
__device__ u32    g_call;                          // bumped after ALL blocks done

constexpr u64   CNT_ONE  = 1ull << 56;
constexpr u64   SUM_MASK = CNT_ONE - 1ull;
constexpr i64   ABIAS    = 1ll << 44;
constexpr float FXS      = 1048576.0f;             // 2^20
constexpr float FXS_INV  = 9.5367431640625e-07f;   // 2^-20

__device__ __forceinline__ u16 f2b(float f) {      // f32 -> bf16 RNE
  u32 x = __float_as_uint(f);
  u32 r = x + 0x7fffu + ((x >> 16) & 1u);
  return (u16)(r >> 16);
}

// NaN-safe clamp + fixed-point encode. Clamp at 8e6 (q <= 8.39e12 < 2^43)
// never binds on the normal path (block partials ~1e4); if the speculative
// trajectory diverges it keeps the count byte clean so verification still
// terminates, and the bad round is detected via the pick mismatch.
__device__ __forceinline__ u64 enc_sum(float s) {
  float sa = s;
  if (!(sa > -8.0e6f)) sa = -8.0e6f;
  if (sa > 8.0e6f)     sa = 8.0e6f;
  return (u64)((i64)(sa * FXS) + ABIAS);
}

// Spin until line's arrival count == CNBX, then decode the exact global sum.
// All pollers read the same final 64-bit value -> identical float -> the
// alpha decision is deterministic and grid-uniform.
template<int SLP>
__device__ __forceinline__ float poll_line(u64* p) {
  u64 v = __hip_atomic_load(p, __ATOMIC_RELAXED, __HIP_MEMORY_SCOPE_AGENT);
  while ((v >> 56) != (u64)CNBX) {
    __builtin_amdgcn_s_sleep(SLP);
    v = __hip_atomic_load(p, __ATOMIC_RELAXED, __HIP_MEMORY_SCOPE_AGENT);
  }
  return (float)((i64)(v & SUM_MASK) - (i64)CNBX * ABIAS) * FXS_INV;
}

// ---- 20-elem vector load/store (coop path). f32: 5x float4 (80B-aligned);
// bf16: 5x uint2 (40B offsets are 8B-aligned). ----
template<bool BF>
__device__ __forceinline__ void load20(const void* p, long long off, float* dst) {
  if (BF) {
    const u16* b = (const u16*)p + off;
#pragma unroll
    for (int i = 0; i < 5; ++i) {
      uint2 a = *(const uint2*)(b + 4*i);
      u32 w0 = a.x, w1 = a.y;
      dst[4*i]   = __uint_as_float((w0 & 0xffffu) << 16);
      dst[4*i+1] = __uint_as_float(w0 & 0xffff0000u);
      dst[4*i+2] = __uint_as_float((w1 & 0xffffu) << 16);
      dst[4*i+3] = __uint_as_float(w1 & 0xffff0000u);
    }
  } else {
    const float* b = (const float*)p + off;
#pragma unroll
    for (int i = 0; i < 5; ++i) {
      float4 v = *(const float4*)(b + 4*i);
      dst[4*i] = v.x; dst[4*i+1] = v.y; dst[4*i+2] = v.z; dst[4*i+3] = v.w;
    }
  }
}

template<bool BF>
__device__ __forceinline__ void store20(void* p, long long off, const float* src) {
  if (BF) {
    u16* b = (u16*)p + off;
#pragma unroll
    for (int i = 0; i < 5; ++i) {
      u32 w0 = (u32)f2b(src[4*i])   | ((u32)f2b(src[4*i+1]) << 16);
      u32 w1 = (u32)f2b(src[4*i+2]) | ((u32)f2b(src[4*i+3]) << 16);
      *(uint2*)(b + 4*i) = make_uint2(w0, w1);
    }
  } else {
    float* b = (float*)p + off;
#pragma unroll
    for (int i = 0; i < 5; ++i)
      *(float4*)(b + 4*i) = make_float4(src[4*i], src[4*i+1], src[4*i+2], src[4*i+3]);
  }
}

// 16-elem versions (fallback path)
template<bool BF>
__device__ __forceinline__ void load16(const void* p, long long off, float* dst) {
  if (BF) {
    const u16* b = (const u16*)p + off;
    uint4 a0 = *(const uint4*)(b);
    uint4 a1 = *(const uint4*)(b + 8);
    u32 w[8] = {a0.x, a0.y, a0.z, a0.w, a1.x, a1.y, a1.z, a1.w};
#pragma unroll
    for (int i = 0; i < 8; ++i) {
      dst[2*i]   = __uint_as_float((w[i] & 0xffffu) << 16);
      dst[2*i+1] = __uint_as_float(w[i] & 0xffff0000u);
    }
  } else {
    const float* b = (const float*)p + off;
#pragma unroll
    for (int i = 0; i < 4; ++i) {
      float4 v = *(const float4*)(b + 4*i);
      dst[4*i] = v.x; dst[4*i+1] = v.y; dst[4*i+2] = v.z; dst[4*i+3] = v.w;
    }
  }
}

template<bool BF>
__device__ __forceinline__ void store16(void* p, long long off, const float* src) {
  if (BF) {
    u16* b = (u16*)p + off;
    u32 w[8];
#pragma unroll
    for (int i = 0; i < 8; ++i)
      w[i] = (u32)f2b(src[2*i]) | ((u32)f2b(src[2*i+1]) << 16);
    *(uint4*)(b)     = make_uint4(w[0], w[1], w[2], w[3]);
    *(uint4*)(b + 8) = make_uint4(w[4], w[5], w[6], w[7]);
  } else {
    float* b = (float*)p + off;
#pragma unroll
    for (int i = 0; i < 4; ++i)
      *(float4*)(b + 4*i) = make_float4(src[4*i], src[4*i+1], src[4*i+2], src[4*i+3]);
  }
}

// dtype probe: k_diag in [1,2). bf16 -> every u16 in [0x3F80,0x4000]; f32 even
// words are random mantissa halves (false-positive p ~ 2e-22 over 8 words).
__device__ __forceinline__ bool probe_bf(const void* KD) {
  const u16* k = (const u16*)KD;
  bool bf = true;
#pragma unroll
  for (int i = 0; i < 8; ++i) {
    u16 v = k[2*i];
    bf = bf && (v >= 0x3F80u && v <= 0x4000u);
  }
  return bf;
}

// Gram-form partials (NE elems/thread): cr(a) = filt*(1+a) - P*a^2 - Q*a^3,
// P=1.2*u*d^2, Q=0.4*d^3, d = -filt/den (exact cubic since den*d = -filt).
// sum cr(a)^2 is a quadratic form in (filt,P,Q) -> 6 sums cover init-norm^2
// and all 6 trial norms. Fixed dofs: filt=0 -> d=P=Q=0.
template<int NE>
__device__ __forceinline__ void compute_gram(bool act, const float* u,
                                             const float* f, const float* kv,
                                             float* du, u32 mbits, float* G) {
#pragma unroll
  for (int j = 0; j < 6; ++j) G[j] = 0.0f;
  if (!act) {
#pragma unroll
    for (int e = 0; e < NE; ++e) du[e] = 0.0f;
    return;
  }
#pragma unroll
  for (int e = 0; e < NE; ++e) {
    const bool fr = ((mbits >> e) & 1u) == 0u;
    const float uu = u[e], ff = f[e], kk = kv[e];
    const float u2 = uu * uu;
    const float g    = fmaf(0.4f * u2, uu, kk * uu);
    const float filt = fr ? (ff - g) : 0.0f;
    const float den  = fmaf(1.2f, u2, kk);
    const float d    = -filt * __builtin_amdgcn_rcpf(den);
    du[e] = d;
    const float d2 = d * d;
    const float P  = (1.2f * uu) * d2;
    const float Q  = (0.4f * d2) * d;
    G[0] = fmaf(filt, filt, G[0]);
    G[1] = fmaf(filt, P,    G[1]);
    G[2] = fmaf(filt, Q,    G[2]);
    G[3] = fmaf(P,    P,    G[3]);
    G[4] = fmaf(P,    Q,    G[4]);
    G[5] = fmaf(Q,    Q,    G[5]);
  }
}

// alpha pick from 6 Gram sums (compare squared; fallback idx 5 == 0.05)
__device__ __forceinline__ int pick_idx(const float* G) {
  const float AL[6] = {1.0f, 0.5f, 0.25f, 0.125f, 0.0625f, 0.05f};
  int idx = 5;
  bool found = false;
#pragma unroll
  for (int t = 0; t < 6; ++t) {
    const float a = AL[t], s = 1.0f + a, a2 = a * a;
    const float n2 = s * s * G[0] - 2.0f * s * a2 * G[1] - 2.0f * s * a2 * a * G[2]
                   + a2 * a2 * G[3] + 2.0f * a2 * a2 * a * G[4]
                   + a2 * a2 * a2 * G[5];
    if (!found && n2 < G[0]) { idx = t; found = true; }
  }
  return idx;
}

// ================= cooperative single-dispatch path =================
// Speculate-then-verify on the line-search pick. Phase 1 runs all NEWTON
// rounds back-to-back with alpha=SPEC_ALPHA and NO waits, streaming each
// round's 6 Gram sums into the arrival-counted lines (fetch_add result
// discarded). OUT is stored speculatively, then ONE verification wait
// decodes all 36 exact global sums and checks pick_idx == SPEC_PICK for
// every round (induction: round n verified => state n+1 exact => round n+1
// sums exact; first mismatch => fallback). Mismatch verdict is computed
// from identical integers in every block -> deterministic, grid-uniform.
__global__ void __launch_bounds__(CTPB, 2) k_coop(const void* __restrict__ F,
                                                  const void* __restrict__ U0,
                                                  const void* __restrict__ KD,
                                                  const int* __restrict__ FIX,
                                                  void* __restrict__ OUT) {
  const int tid = threadIdx.x, bid = blockIdx.x;
  const int b = bid / CNBX, bx = bid - b * CNBX;
  const int d0 = bx * CEPB + tid * CEPT;
  const bool act = (d0 + CEPT <= DOF);      // threads are full-vec or inactive
  const long long gb = (long long)b * DOF + d0;
  const bool bf = probe_bf(KD);
  const float ALTAB[6] = {1.0f, 0.5f, 0.25f, 0.125f, 0.0625f, 0.05f};

  __shared__ u32   mw[CEPB / 32 + 1];       // +1 pad word for 20-bit extraction
  __shared__ float sred[2][CTPB / 64][8];   // round-parity double buffer
  __shared__ float sG[NEWTON * 6];          // verified global sums
  __shared__ float gG[6];                   // fallback per-round sums
  __shared__ u32   sflag;

  // parity select; previous call fully retired (stream-serialized), so its
  // g_call bump is visible via the dispatch boundary.
  const u32 call = __hip_atomic_load(&g_call, __ATOMIC_RELAXED,
                                     __HIP_MEMORY_SCOPE_AGENT);
  const int par  = (int)(call & 1u);

  // prefetch inputs first: overlap HBM latency with resets + mask build
  float u[CEPT], f[CEPT], kv[CEPT], du[CEPT];
  if (act) {
    if (bf) { load20<true >(U0, gb, u); load20<true >(F, gb, f); load20<true >(KD, d0, kv); }
    else    { load20<false>(U0, gb, u); load20<false>(F, gb, f); load20<false>(KD, d0, kv); }
  }

  // zero the OTHER parity's banks (their last user, call-1, fully retired):
  // 2*288 lines across 240 blocks = <=3 stores per block, off critical path.
  if (tid == 0) {
    for (int L = bid; L < 2 * NLINES; L += CGRID) {
      const int s  = L / NLINES;
      const int r  = L % NLINES;
      const int n2 = r / (NB * 6), rr = r % (NB * 6);
      u64* p = s ? &g_facc[par ^ 1][n2][rr / 6][rr % 6].v
                 : &g_acc [par ^ 1][n2][rr / 6][rr % 6].v;
      __hip_atomic_store(p, 0ull, __ATOMIC_RELAXED, __HIP_MEMORY_SCOPE_AGENT);
    }
    if (bid == 0)
      __hip_atomic_store(&g_done[par ^ 1].v, 0ull,
                         __ATOMIC_RELAXED, __HIP_MEMORY_SCOPE_AGENT);
  }

  // block-local fixed-dof bitmask over this block's 10240-dof window
  for (int i = tid; i < CEPB / 32 + 1; i += CTPB) mw[i] = 0u;
  __syncthreads();
  const int blk_base = bx * CEPB;
  for (int i = tid; i < NFIX; i += CTPB) {
    const int d = FIX[i] - blk_base;
    if (d >= 0 && d < CEPB) atomicOr(&mw[d >> 5], 1u << (d & 31));
  }
  __syncthreads();
  const int off = tid * CEPT;                // 20 bits, may span 2 words
  const u64 mm = (((u64)mw[(off >> 5) + 1] << 32) | (u64)mw[off >> 5]) >> (off & 31);
  const u32 mbits = (u32)mm & 0xFFFFFu;

  // ------- phase 1: alpha=SPEC_ALPHA trajectory, one sync per round -------
  for (int n = 0; n < NEWTON; ++n) {
    const int rp = n & 1;
    float G[6];
    compute_gram<CEPT>(act, u, f, kv, du, mbits, G);
    { // 8-wave block reduce into sred[rp][*][j]
      const int lane = tid & 63, wid = tid >> 6;
#pragma unroll
      for (int j = 0; j < 6; ++j) {
        float v = G[j];
#pragma unroll
        for (int o = 32; o > 0; o >>= 1) v += __shfl_down(v, o, 64);
        if (lane == 0) sred[rp][wid][j] = v;
      }
      __syncthreads();   // sred[rp] complete; WAR vs round n+2 is covered by
                         // the round n+1 barrier (double buffer)
    }
    if (tid < 6) {                           // fire-and-forget arrival+sum
      float s = sred[rp][0][tid];
#pragma unroll
      for (int w2 = 1; w2 < CTPB / 64; ++w2) s += sred[rp][w2][tid];
      (void)__hip_atomic_fetch_add(&g_acc[par][n][b][tid].v,
                                   CNT_ONE | enc_sum(s), __ATOMIC_RELAXED,
                                   __HIP_MEMORY_SCOPE_AGENT);
    }
    if (act) {
#pragma unroll
      for (int e = 0; e < CEPT; ++e) u[e] = fmaf(SPEC_ALPHA, du[e], u[e]);
    }
  }

  // speculative store: overlaps the verification wait; fallback overwrites.
  if (act) {
    if (bf) store20<true >(OUT, gb, u);
    else    store20<false>(OUT, gb, u);
  }

  // ---------------- single verification wait ----------------
  if (tid < NEWTON * 6) {
    const int n = tid / 6, j = tid - n * 6;
    sG[tid] = poll_line<2>(&g_acc[par][n][b][j].v);
  }
  __syncthreads();
  if (tid == 0) {
    u32 ok = 1u;
#pragma unroll
    for (int n = 0; n < NEWTON; ++n)
      ok &= (pick_idx(&sG[6 * n]) == SPEC_PICK) ? 1u : 0u;
    sflag = ok;
  }
  __syncthreads();

  if (!sflag) {
    // ------------- fallback: exact synced loop (rare path) -------------
    if (act) {
      if (bf) load20<true >(U0, gb, u);
      else    load20<false>(U0, gb, u);
    }
    for (int n = 0; n < NEWTON; ++n) {
      float G[6];
      compute_gram<CEPT>(act, u, f, kv, du, mbits, G);
      {
        const int lane = tid & 63, wid = tid >> 6;
#pragma unroll
        for (int j = 0; j < 6; ++j) {
          float v = G[j];
#pragma unroll
          for (int o = 32; o > 0; o >>= 1) v += __shfl_down(v, o, 64);
          if (lane == 0) sred[0][wid][j] = v;
        }
        __syncthreads();
      }
      if (tid < 6) {
        float s = sred[0][0][tid];
#pragma unroll
        for (int w2 = 1; w2 < CTPB / 64; ++w2) s += sred[0][w2][tid];
        (void)__hip_atomic_fetch_add(&g_facc[par][n][b][tid].v,
                                     CNT_ONE | enc_sum(s), __ATOMIC_RELAXED,
                                     __HIP_MEMORY_SCOPE_AGENT);
        gG[tid] = poll_line<8>(&g_facc[par][n][b][tid].v);   // direct-line poll
      }
      __syncthreads();
      float GG[6];
#pragma unroll
      for (int j = 0; j < 6; ++j) GG[j] = gG[j];
      const float ab = ALTAB[pick_idx(GG)];
      if (act) {
#pragma unroll
        for (int e = 0; e < CEPT; ++e) u[e] = fmaf(ab, du[e], u[e]);
      }
      __syncthreads();                       // sred/gG WAR vs next round
    }
    if (act) {
      if (bf) store20<true >(OUT, gb, u);
      else    store20<false>(OUT, gb, u);
    }
  }

  // g_call bump gated on ALL 240 blocks finishing.
  if (tid == 0) {
    const u64 old = __hip_atomic_fetch_add(&g_done[par].v, 1ull,
                                           __ATOMIC_RELAXED,
                                           __HIP_MEMORY_SCOPE_AGENT);
    if (old == (u64)(CGRID - 1))
      __hip_atomic_store(&g_call, call + 1u, __ATOMIC_RELAXED,
                         __HIP_MEMORY_SCOPE_AGENT);
  }
}

// ============ fallback multi-kernel path (proven 256/16/74 shape) ============
__device__ __forceinline__ u32 build_mask_fb(const int* __restrict__ FIX,
                                             int blk_base, int tid, u32* mw) {
  for (int i = tid; i < FEPB / 32; i += FTPB) mw[i] = 0u;
  __syncthreads();
  for (int i = tid; i < NFIX; i += FTPB) {
    const int d = FIX[i] - blk_base;
    if (d >= 0 && d < FEPB) atomicOr(&mw[d >> 5], 1u << (d & 31));
  }
  __syncthreads();
  const int off = tid * FEPT;
  return (mw[off >> 5] >> (off & 31)) & 0xFFFFu;
}

__device__ __forceinline__ void compute_partials7(bool act, const float* u,
                                                  const float* f, const float* kv,
                                                  float* du, u32 mbits, float* part) {
#pragma unroll
  for (int j = 0; j < 7; ++j) part[j] = 0.0f;
  const float AL[6] = {1.0f, 0.5f, 0.25f, 0.125f, 0.0625f, 0.05f};
  if (!act) {
#pragma unroll
    for (int e = 0; e < FEPT; ++e) du[e] = 0.0f;
    return;
  }
#pragma unroll
  for (int e = 0; e < FEPT; ++e) {
    const bool fr = ((mbits >> e) & 1u) == 0u;
    const float uu = u[e], ff = f[e], kk = kv[e];
    const float u2 = uu * uu;
    const float g    = fmaf(0.4f * u2, uu, kk * uu);
    const float filt = fr ? (ff - g) : 0.0f;
    part[0] = fmaf(filt, filt, part[0]);
    const float den = fmaf(1.2f, u2, kk);
    const float d   = -filt * __builtin_amdgcn_rcpf(den);
    du[e] = d;
    const float d2  = d * d;
    const float Bc  = 1.2f * uu * d2;
    const float Cc  = 0.4f * d2 * d;
#pragma unroll
    for (int t = 0; t < 6; ++t) {
      const float a  = AL[t];
      const float cr = fmaf(a, fmaf(a, fmaf(-Cc, a, -Bc), filt), filt);
      part[1 + t] = fmaf(cr, cr, part[1 + t]);
    }
  }
}

__device__ __forceinline__ float sum_pick_fb(float (*red)[8], int n, int b, int tid) {
  if (tid < FNBX) {
#pragma unroll
    for (int j = 0; j < 7; ++j)
      red[tid][j] = __hip_atomic_load(&g_part[n][b][tid][j], __ATOMIC_RELAXED,
                                      __HIP_MEMORY_SCOPE_AGENT);
  }
  __syncthreads();
#pragma unroll
  for (int s = 64; s >= 1; s >>= 1) {
    if (tid < s && tid + s < FNBX) {
#pragma unroll
      for (int j = 0; j < 7; ++j) red[tid][j] += red[tid + s][j];
    }
    __syncthreads();
  }
  const float initn = sqrtf(red[0][0]);
  const float AL[6] = {1.0f, 0.5f, 0.25f, 0.125f, 0.0625f, 0.05f};
  float ab = 0.05f;
  bool found = false;
#pragma unroll
  for (int t = 0; t < 6; ++t) {
    const float nt = sqrtf(red[0][1 + t]);
    if (!found && nt < initn) { ab = AL[t]; found = true; }
  }
  __syncthreads();
  return ab;
}

template<bool BF>
__device__ __forceinline__ void load_state_fb(const void* U0, const void* F,
                                              const void* KD, int n, long long gb,
                                              int d0, float* u, float* f, float* kv) {
  if (n == 0) load16<BF>(U0, gb, u);
  else {
#pragma unroll
    for (int i = 0; i < 4; ++i) {
      float4 q = *(const float4*)(g_UW + gb + 4*i);
      u[4*i] = q.x; u[4*i+1] = q.y; u[4*i+2] = q.z; u[4*i+3] = q.w;
    }
  }
  load16<BF>(F, gb, f);
  load16<BF>(KD, d0, kv);
}

__global__ void __launch_bounds__(FTPB) k_part_fb(const void* __restrict__ F,
                                                  const void* __restrict__ U0,
                                                  const void* __restrict__ KD,
                                                  const int* __restrict__ FIX, int n) {
  const int tid = threadIdx.x, bid = blockIdx.x;
  const int b = bid / FNBX, bx = bid - b * FNBX;
  const int d0 = bx * FEPB + tid * FEPT;
  const bool act = (d0 < DOF);
  const long long gb = (long long)b * DOF + d0;
  const bool bf = probe_bf(KD);
  __shared__ u32   mw[FEPB / 32];
  __shared__ float sred[FTPB / 64][8];
  const u32 mbits = build_mask_fb(FIX, bx * FEPB, tid, mw);
  float u[FEPT], f[FEPT], kv[FEPT], du[FEPT];
  if (act) {
    if (bf) load_state_fb<true >(U0, F, KD, n, gb, d0, u, f, kv);
    else    load_state_fb<false>(U0, F, KD, n, gb, d0, u, f, kv);
  }
  float part[7];
  compute_partials7(act, u, f, kv, du, mbits, part);
  const int lane = tid & 63, wid = tid >> 6;
#pragma unroll
  for (int j = 0; j < 7; ++j) {
    float v = part[j];
#pragma unroll
    for (int o = 32; o > 0; o >>= 1) v += __shfl_down(v, o, 64);
    if (lane == 0) sred[wid][j] = v;
  }
  __syncthreads();
  if (tid < 7)
    g_part[n][b][bx][tid] = sred[0][tid] + sred[1][tid] + sred[2][tid] + sred[3][tid];
}

__global__ void __launch_bounds__(FTPB) k_upd_fb(const void* __restrict__ F,
                                                 const void* __restrict__ U0,
                                                 const void* __restrict__ KD,
                                                 const int* __restrict__ FIX,
                                                 void* __restrict__ OUT, int n, int last) {
  const int tid = threadIdx.x, bid = blockIdx.x;
  const int b = bid / FNBX, bx = bid - b * FNBX;
  const int d0 = bx * FEPB + tid * FEPT;
  const bool act = (d0 < DOF);
  const long long gb = (long long)b * DOF + d0;
  const bool bf = probe_bf(KD);
  __shared__ u32   mw[FEPB / 32];
  __shared__ float red[80][8];
  const u32 mbits = build_mask_fb(FIX, bx * FEPB, tid, mw);
  const float ab = sum_pick_fb(red, n, b, tid);
  if (!act) return;
  float u[FEPT], f[FEPT], kv[FEPT], du[FEPT];
  if (bf) load_state_fb<true >(U0, F, KD, n, gb, d0, u, f, kv);
  else    load_state_fb<false>(U0, F, KD, n, gb, d0, u, f, kv);
  float part[7];
  compute_partials7(act, u, f, kv, du, mbits, part);   // recompute du
#pragma unroll
  for (int e = 0; e < FEPT; ++e) u[e] = fmaf(ab, du[e], u[e]);
#pragma unroll
  for (int i = 0; i < 4; ++i)
    *(float4*)(g_UW + gb + 4*i) = make_float4(u[4*i], u[4*i+1], u[4*i+2], u[4*i+3]);
  if (last) {
    if (bf) store16<true >(OUT, gb, u);
    else    store16<false>(OUT, gb, u);
  }
}

extern "C" void kernel_launch(void* const* d_in, const int* in_sizes, int n_in,
                              void* d_out, int out_size, void* d_ws, size_t ws_size,
                              hipStream_t stream) {
  const void* F   = d_in[0];               // external_forces [B, DOF]
  const void* U0  = d_in[1];               // u0              [B, DOF]
  const void* KD  = d_in[2];               // k_diag          [DOF]
  const int*  FIX = (const int*)d_in[3];   // fixed_dofs      [NFIX] int32
  void* OUT = d_out;

  void* args[] = {(void*)&F, (void*)&U0, (void*)&KD, (void*)&FIX, (void*)&OUT};
  hipError_t e = hipLaunchCooperativeKernel((void*)k_coop, dim3(CGRID), dim3(CTPB),
                                            args, 0, stream);
  if (e != hipSuccess) {
    (void)hipGetLastError();               // clear sticky error, take fallback
    for (int n = 0; n < NEWTON; ++n) {
      k_part_fb<<<FGRID, FTPB, 0, stream>>>(F, U0, KD, FIX, n);
      k_upd_fb<<<FGRID, FTPB, 0, stream>>>(F, U0, KD, FIX, d_out, n,
                                           (n == NEWTON - 1) ? 1 : 0);
    }
  }
}

// Round 3
// 121.799 us; speedup vs baseline: 1.2616x; 1.0148x over previous
//
#include <hip/hip_runtime.h>

typedef unsigned short u16;
typedef unsigned int   u32;
typedef unsigned long long u64;
typedef long long i64;

constexpr int DOF    = 300000;
constexpr int NB     = 8;
constexpr int NFIX   = 3000;
constexpr int NEWTON = 6;

// ---- cooperative config: 392 blocks x 512 thr x 12 elem = 2 blocks/CU ----
// Coalesced chunking: thread owns CCH float4-chunks at lane-consecutive
// positions (c*CTPB+tid)*4 -> every global load/store is 64x16B contiguous.
constexpr int CTPB  = 512;
constexpr int CCH   = 3;                           // float4 chunks / thread
constexpr int CEPT  = CCH * 4;                     // 12
constexpr int CEPB  = CTPB * CEPT;                 // 6144
constexpr int CNBX  = (DOF + CEPB - 1) / CEPB;     // 49 blocks per batch
constexpr int CGRID = CNBX * NB;                   // 392 (<=512 co-resident)
constexpr int NLINES = NEWTON * NB * 6;            // 288 acc lines per bank

// Speculated line-search outcome (HW-verified in round 2: pick==5 passes
// verification on every call). The reference solves A*du = -filtered
// (du = -H^-1 r, ASCENT direction): no trial alpha reduces the norm ->
// any_imp=False -> alpha=ALPHA_MIN=0.05 (pick_idx==5) every round.
constexpr int   SPEC_PICK  = 5;
constexpr float SPEC_ALPHA = 0.05f;

// ---- fallback config (proven multi-kernel shape) ----
constexpr int FTPB  = 256;
constexpr int FEPT  = 16;
constexpr int FEPB  = FTPB * FEPT;                 // 4096
constexpr int FNBX  = (DOF + FEPB - 1) / FEPB;     // 74
constexpr int FGRID = FNBX * NB;                   // 592

// ---- static device scratch (no d_ws dependence; .bss zero-init) ----
__device__ float g_part[NEWTON][NB][FNBX][8];      // fallback only
__device__ float g_UW[NB * DOF];                   // fallback only

// acc line: u64, top byte = arrival count, low 56 = biased fixed-point sum
// (scale 2^20, per-add bias 2^44; 49 adds: bias 49*2^44, worst-case clamped
// magnitude 49*(2^44+2^43) < 2^56). Count byte == CNBX is the publication:
// pollers read lines directly. g_acc = speculative rounds, g_facc = exact
// synced fallback rounds. Parity-banked across calls; the current call's
// banks were zeroed by the previous call (stream-serialized).
struct alignas(64) PadU64 { u64 v; u64 pad[7]; };
__device__ PadU64 g_acc [2][NEWTON][NB][6];
__device__ PadU64 g_facc[2][NEWTON][NB][6];
__device__ PadU64 g_done[2];                       // parity-banked finish count
__device__ u32    g_call;                          // bumped after ALL blocks done

constexpr u64   CNT_ONE  = 1ull << 56;
constexpr u64   SUM_MASK = CNT_ONE - 1ull;
constexpr i64   ABIAS    = 1ll << 44;
constexpr float FXS      = 1048576.0f;             // 2^20
constexpr float FXS_INV  = 9.5367431640625e-07f;   // 2^-20

__device__ __forceinline__ u16 f2b(float f) {      // f32 -> bf16 RNE
  u32 x = __float_as_uint(f);
  u32 r = x + 0x7fffu + ((x >> 16) & 1u);
  return (u16)(r >> 16);
}

// NaN-safe clamp + fixed-point encode. Clamp at 8e6 never binds on the
// normal path (block partials ~1e4); if the speculative trajectory diverges
// it keeps the count byte clean so verification still terminates, and the
// bad round is detected via the pick mismatch.
__device__ __forceinline__ u64 enc_sum(float s) {
  float sa = s;
  if (!(sa > -8.0e6f)) sa = -8.0e6f;
  if (sa > 8.0e6f)     sa = 8.0e6f;
  return (u64)((i64)(sa * FXS) + ABIAS);
}

// Spin until line's arrival count == CNBX, then decode the exact global sum.
// All pollers read the same final 64-bit value -> identical float -> the
// alpha decision is deterministic and grid-uniform.
template<int SLP>
__device__ __forceinline__ float poll_line(u64* p) {
  u64 v = __hip_atomic_load(p, __ATOMIC_RELAXED, __HIP_MEMORY_SCOPE_AGENT);
  while ((v >> 56) != (u64)CNBX) {
    __builtin_amdgcn_s_sleep(SLP);
    v = __hip_atomic_load(p, __ATOMIC_RELAXED, __HIP_MEMORY_SCOPE_AGENT);
  }
  return (float)((i64)(v & SUM_MASK) - (i64)CNBX * ABIAS) * FXS_INV;
}

// ---- 4-elem chunk load/store (coop path). f32: float4 (16B-aligned);
// bf16: uint2 (8B-aligned). Lane-consecutive chunks -> fully coalesced. ----
template<bool BF>
__device__ __forceinline__ void load4(const void* p, long long eoff, float* dst) {
  if (BF) {
    const u16* b = (const u16*)p + eoff;
    uint2 a = *(const uint2*)b;
    dst[0] = __uint_as_float((a.x & 0xffffu) << 16);
    dst[1] = __uint_as_float(a.x & 0xffff0000u);
    dst[2] = __uint_as_float((a.y & 0xffffu) << 16);
    dst[3] = __uint_as_float(a.y & 0xffff0000u);
  } else {
    float4 v = *(const float4*)((const float*)p + eoff);
    dst[0] = v.x; dst[1] = v.y; dst[2] = v.z; dst[3] = v.w;
  }
}

template<bool BF>
__device__ __forceinline__ void store4(void* p, long long eoff, const float* s) {
  if (BF) {
    u16* b = (u16*)p + eoff;
    *(uint2*)b = make_uint2((u32)f2b(s[0]) | ((u32)f2b(s[1]) << 16),
                            (u32)f2b(s[2]) | ((u32)f2b(s[3]) << 16));
  } else {
    *(float4*)((float*)p + eoff) = make_float4(s[0], s[1], s[2], s[3]);
  }
}

// 16-elem versions (multi-kernel fallback path)
template<bool BF>
__device__ __forceinline__ void load16(const void* p, long long off, float* dst) {
  if (BF) {
    const u16* b = (const u16*)p + off;
    uint4 a0 = *(const uint4*)(b);
    uint4 a1 = *(const uint4*)(b + 8);
    u32 w[8] = {a0.x, a0.y, a0.z, a0.w, a1.x, a1.y, a1.z, a1.w};
#pragma unroll
    for (int i = 0; i < 8; ++i) {
      dst[2*i]   = __uint_as_float((w[i] & 0xffffu) << 16);
      dst[2*i+1] = __uint_as_float(w[i] & 0xffff0000u);
    }
  } else {
    const float* b = (const float*)p + off;
#pragma unroll
    for (int i = 0; i < 4; ++i) {
      float4 v = *(const float4*)(b + 4*i);
      dst[4*i] = v.x; dst[4*i+1] = v.y; dst[4*i+2] = v.z; dst[4*i+3] = v.w;
    }
  }
}

template<bool BF>
__device__ __forceinline__ void store16(void* p, long long off, const float* src) {
  if (BF) {
    u16* b = (u16*)p + off;
    u32 w[8];
#pragma unroll
    for (int i = 0; i < 8; ++i)
      w[i] = (u32)f2b(src[2*i]) | ((u32)f2b(src[2*i+1]) << 16);
    *(uint4*)(b)     = make_uint4(w[0], w[1], w[2], w[3]);
    *(uint4*)(b + 8) = make_uint4(w[4], w[5], w[6], w[7]);
  } else {
    float* b = (float*)p + off;
#pragma unroll
    for (int i = 0; i < 4; ++i)
      *(float4*)(b + 4*i) = make_float4(src[4*i], src[4*i+1], src[4*i+2], src[4*i+3]);
  }
}

// dtype probe: k_diag in [1,2). bf16 -> every u16 in [0x3F80,0x4000]; f32 even
// words are random mantissa halves (false-positive p ~ 2e-22 over 8 words).
__device__ __forceinline__ bool probe_bf(const void* KD) {
  const u16* k = (const u16*)KD;
  bool bf = true;
#pragma unroll
  for (int i = 0; i < 8; ++i) {
    u16 v = k[2*i];
    bf = bf && (v >= 0x3F80u && v <= 0x4000u);
  }
  return bf;
}

// Gram-form partials: cr(a) = filt*(1+a) - P*a^2 - Q*a^3, P=1.2*u*d^2,
// Q=0.4*d^3, d = -filt/den (exact cubic since den*d = -filt). sum cr(a)^2
// is a quadratic form in (filt,P,Q) -> 6 sums cover init-norm^2 and all 6
// trial norms. Fixed dofs: filt=0 -> d=P=Q=0. Inactive chunks are loaded
// with u=f=0, kv=1 -> filt=0 -> contribute nothing, du=0.
template<int NE>
__device__ __forceinline__ void compute_gram(const float* u, const float* f,
                                             const float* kv, float* du,
                                             u32 mbits, float* G) {
#pragma unroll
  for (int j = 0; j < 6; ++j) G[j] = 0.0f;
#pragma unroll
  for (int e = 0; e < NE; ++e) {
    const bool fr = ((mbits >> e) & 1u) == 0u;
    const float uu = u[e], ff = f[e], kk = kv[e];
    const float u2 = uu * uu;
    const float g    = fmaf(0.4f * u2, uu, kk * uu);
    const float filt = fr ? (ff - g) : 0.0f;
    const float den  = fmaf(1.2f, u2, kk);
    const float d    = -filt * __builtin_amdgcn_rcpf(den);
    du[e] = d;
    const float d2 = d * d;
    const float P  = (1.2f * uu) * d2;
    const float Q  = (0.4f * d2) * d;
    G[0] = fmaf(filt, filt, G[0]);
    G[1] = fmaf(filt, P,    G[1]);
    G[2] = fmaf(filt, Q,    G[2]);
    G[3] = fmaf(P,    P,    G[3]);
    G[4] = fmaf(P,    Q,    G[4]);
    G[5] = fmaf(Q,    Q,    G[5]);
  }
}

// alpha pick from 6 Gram sums (compare squared; fallback idx 5 == 0.05)
__device__ __forceinline__ int pick_idx(const float* G) {
  const float AL[6] = {1.0f, 0.5f, 0.25f, 0.125f, 0.0625f, 0.05f};
  int idx = 5;
  bool found = false;
#pragma unroll
  for (int t = 0; t < 6; ++t) {
    const float a = AL[t], s = 1.0f + a, a2 = a * a;
    const float n2 = s * s * G[0] - 2.0f * s * a2 * G[1] - 2.0f * s * a2 * a * G[2]
                   + a2 * a2 * G[3] + 2.0f * a2 * a2 * a * G[4]
                   + a2 * a2 * a2 * G[5];
    if (!found && n2 < G[0]) { idx = t; found = true; }
  }
  return idx;
}

// ================= cooperative single-dispatch path =================
// Speculate-then-verify on the line-search pick (HW-proven in round 2).
// Phase 1 runs all NEWTON rounds back-to-back with alpha=SPEC_ALPHA,
// streaming each round's 6 Gram sums into the arrival-counted lines
// (fetch_add result discarded). OUT is stored speculatively, then ONE
// verification wait decodes all 36 exact global sums and checks
// pick_idx == SPEC_PICK per round (induction: round n verified => state
// n+1 exact => round n+1 sums exact; first mismatch => fallback). The
// verdict is computed from identical integers in every block ->
// deterministic, grid-uniform.
__global__ void __launch_bounds__(CTPB, 4) k_coop(const void* __restrict__ F,
                                                  const void* __restrict__ U0,
                                                  const void* __restrict__ KD,
                                                  const int* __restrict__ FIX,
                                                  void* __restrict__ OUT) {
  const int tid = threadIdx.x, bid = blockIdx.x;
  const int b = bid / CNBX, bx = bid - b * CNBX;
  const int blk_base = bx * CEPB;
  const bool bf = probe_bf(KD);
  const float ALTAB[6] = {1.0f, 0.5f, 0.25f, 0.125f, 0.0625f, 0.05f};

  __shared__ u32   mw[CEPB / 32];           // 4-aligned nibbles never span words
  __shared__ float sred[2][CTPB / 64][8];   // round-parity double buffer
  __shared__ float sG[NEWTON * 6];          // verified global sums
  __shared__ float gG[8];                   // fallback per-round sums
  __shared__ u32   sflag;

  // parity select; previous call fully retired (stream-serialized), so its
  // g_call bump is visible via the dispatch boundary.
  const u32 call = __hip_atomic_load(&g_call, __ATOMIC_RELAXED,
                                     __HIP_MEMORY_SCOPE_AGENT);
  const int par  = (int)(call & 1u);

  // chunk geometry: chunk c covers elements blk_base + (c*CTPB+tid)*4 .. +3
  int  cpos[CCH];
  bool ok[CCH];
#pragma unroll
  for (int c = 0; c < CCH; ++c) {
    cpos[c] = (c * CTPB + tid) * 4;
    ok[c]   = (blk_base + cpos[c] + 4 <= DOF);
  }

  // prefetch inputs first (fully coalesced): overlap HBM latency with
  // resets + mask build. Inactive chunks get neutral values.
  float u[CEPT], f[CEPT], kv[CEPT], du[CEPT];
#pragma unroll
  for (int c = 0; c < CCH; ++c) {
    const long long ge = (long long)b * DOF + blk_base + cpos[c];
    const long long ke = blk_base + cpos[c];
    if (ok[c]) {
      if (bf) { load4<true >(U0, ge, &u[4*c]); load4<true >(F, ge, &f[4*c]); load4<true >(KD, ke, &kv[4*c]); }
      else    { load4<false>(U0, ge, &u[4*c]); load4<false>(F, ge, &f[4*c]); load4<false>(KD, ke, &kv[4*c]); }
    } else {
#pragma unroll
      for (int j = 0; j < 4; ++j) { u[4*c+j] = 0.0f; f[4*c+j] = 0.0f; kv[4*c+j] = 1.0f; }
    }
  }

  // zero the OTHER parity's banks (their last user, call-1, fully retired):
  // 2*288 lines across 392 blocks = <=2 stores per block, off critical path.
  if (tid == 0) {
    for (int L = bid; L < 2 * NLINES; L += CGRID) {
      const int s  = L / NLINES;
      const int r  = L % NLINES;
      const int n2 = r / (NB * 6), rr = r % (NB * 6);
      u64* p = s ? &g_facc[par ^ 1][n2][rr / 6][rr % 6].v
                 : &g_acc [par ^ 1][n2][rr / 6][rr % 6].v;
      __hip_atomic_store(p, 0ull, __ATOMIC_RELAXED, __HIP_MEMORY_SCOPE_AGENT);
    }
    if (bid == 0)
      __hip_atomic_store(&g_done[par ^ 1].v, 0ull,
                         __ATOMIC_RELAXED, __HIP_MEMORY_SCOPE_AGENT);
  }

  // block-local fixed-dof bitmask over this block's 6144-dof window
  for (int i = tid; i < CEPB / 32; i += CTPB) mw[i] = 0u;
  __syncthreads();
  for (int i = tid; i < NFIX; i += CTPB) {
    const int d = FIX[i] - blk_base;
    if (d >= 0 && d < CEPB) atomicOr(&mw[d >> 5], 1u << (d & 31));
  }
  __syncthreads();
  u32 mbits = 0u;
#pragma unroll
  for (int c = 0; c < CCH; ++c) {
    const int pos = cpos[c];
    mbits |= ((mw[pos >> 5] >> (pos & 31)) & 0xFu) << (4 * c);
  }

  // ------- phase 1: alpha=SPEC_ALPHA trajectory, one sync per round -------
  for (int n = 0; n < NEWTON; ++n) {
    const int rp = n & 1;
    float G[6];
    compute_gram<CEPT>(u, f, kv, du, mbits, G);
    { // 8-wave block reduce into sred[rp][*][j]
      const int lane = tid & 63, wid = tid >> 6;
#pragma unroll
      for (int j = 0; j < 6; ++j) {
        float v = G[j];
#pragma unroll
        for (int o = 32; o > 0; o >>= 1) v += __shfl_down(v, o, 64);
        if (lane == 0) sred[rp][wid][j] = v;
      }
      __syncthreads();   // sred[rp] complete; WAR vs round n+2 is covered by
                         // the round n+1 barrier (double buffer)
    }
    if (tid < 6) {                           // fire-and-forget arrival+sum
      float s = sred[rp][0][tid];
#pragma unroll
      for (int w2 = 1; w2 < CTPB / 64; ++w2) s += sred[rp][w2][tid];
      (void)__hip_atomic_fetch_add(&g_acc[par][n][b][tid].v,
                                   CNT_ONE | enc_sum(s), __ATOMIC_RELAXED,
                                   __HIP_MEMORY_SCOPE_AGENT);
    }
#pragma unroll
    for (int e = 0; e < CEPT; ++e) u[e] = fmaf(SPEC_ALPHA, du[e], u[e]);
  }

  // speculative store: overlaps the verification wait; fallback overwrites.
#pragma unroll
  for (int c = 0; c < CCH; ++c) {
    if (ok[c]) {
      const long long ge = (long long)b * DOF + blk_base + cpos[c];
      if (bf) store4<true >(OUT, ge, &u[4*c]);
      else    store4<false>(OUT, ge, &u[4*c]);
    }
  }

  // ---------------- single verification wait ----------------
  if (tid < NEWTON * 6) {
    const int n = tid / 6, j = tid - n * 6;
    sG[tid] = poll_line<2>(&g_acc[par][n][b][j].v);
  }
  __syncthreads();
  if (tid == 0) {
    u32 okf = 1u;
#pragma unroll
    for (int n = 0; n < NEWTON; ++n)
      okf &= (pick_idx(&sG[6 * n]) == SPEC_PICK) ? 1u : 0u;
    sflag = okf;
  }
  __syncthreads();

  if (!sflag) {
    // ------------- fallback: exact synced loop (rare path) -------------
#pragma unroll
    for (int c = 0; c < CCH; ++c) {         // reload u0 (inactive stay 0)
      if (ok[c]) {
        const long long ge = (long long)b * DOF + blk_base + cpos[c];
        if (bf) load4<true >(U0, ge, &u[4*c]);
        else    load4<false>(U0, ge, &u[4*c]);
      }
    }
    for (int n = 0; n < NEWTON; ++n) {
      float G[6];
      compute_gram<CEPT>(u, f, kv, du, mbits, G);
      {
        const int lane = tid & 63, wid = tid >> 6;
#pragma unroll
        for (int j = 0; j < 6; ++j) {
          float v = G[j];
#pragma unroll
          for (int o = 32; o > 0; o >>= 1) v += __shfl_down(v, o, 64);
          if (lane == 0) sred[0][wid][j] = v;
        }
        __syncthreads();
      }
      if (tid < 6) {
        float s = sred[0][0][tid];
#pragma unroll
        for (int w2 = 1; w2 < CTPB / 64; ++w2) s += sred[0][w2][tid];
        (void)__hip_atomic_fetch_add(&g_facc[par][n][b][tid].v,
                                     CNT_ONE | enc_sum(s), __ATOMIC_RELAXED,
                                     __HIP_MEMORY_SCOPE_AGENT);
        gG[tid] = poll_line<8>(&g_facc[par][n][b][tid].v);   // direct-line poll
      }
      __syncthreads();
      float GG[6];
#pragma unroll
      for (int j = 0; j < 6; ++j) GG[j] = gG[j];
      const float ab = ALTAB[pick_idx(GG)];
#pragma unroll
      for (int e = 0; e < CEPT; ++e) u[e] = fmaf(ab, du[e], u[e]);
      __syncthreads();                       // sred/gG WAR vs next round
    }
#pragma unroll
    for (int c = 0; c < CCH; ++c) {
      if (ok[c]) {
        const long long ge = (long long)b * DOF + blk_base + cpos[c];
        if (bf) store4<true >(OUT, ge, &u[4*c]);
        else    store4<false>(OUT, ge, &u[4*c]);
      }
    }
  }

  // g_call bump gated on ALL 392 blocks finishing.
  if (tid == 0) {
    const u64 old = __hip_atomic_fetch_add(&g_done[par].v, 1ull,
                                           __ATOMIC_RELAXED,
                                           __HIP_MEMORY_SCOPE_AGENT);
    if (old == (u64)(CGRID - 1))
      __hip_atomic_store(&g_call, call + 1u, __ATOMIC_RELAXED,
                         __HIP_MEMORY_SCOPE_AGENT);
  }
}

// ============ fallback multi-kernel path (proven 256/16/74 shape) ============
__device__ __forceinline__ u32 build_mask_fb(const int* __restrict__ FIX,
                                             int blk_base, int tid, u32* mw) {
  for (int i = tid; i < FEPB / 32; i += FTPB) mw[i] = 0u;
  __syncthreads();
  for (int i = tid; i < NFIX; i += FTPB) {
    const int d = FIX[i] - blk_base;
    if (d >= 0 && d < FEPB) atomicOr(&mw[d >> 5], 1u << (d & 31));
  }
  __syncthreads();
  const int off = tid * FEPT;
  return (mw[off >> 5] >> (off & 31)) & 0xFFFFu;
}

__device__ __forceinline__ void compute_partials7(bool act, const float* u,
                                                  const float* f, const float* kv,
                                                  float* du, u32 mbits, float* part) {
#pragma unroll
  for (int j = 0; j < 7; ++j) part[j] = 0.0f;
  const float AL[6] = {1.0f, 0.5f, 0.25f, 0.125f, 0.0625f, 0.05f};
  if (!act) {
#pragma unroll
    for (int e = 0; e < FEPT; ++e) du[e] = 0.0f;
    return;
  }
#pragma unroll
  for (int e = 0; e < FEPT; ++e) {
    const bool fr = ((mbits >> e) & 1u) == 0u;
    const float uu = u[e], ff = f[e], kk = kv[e];
    const float u2 = uu * uu;
    const float g    = fmaf(0.4f * u2, uu, kk * uu);
    const float filt = fr ? (ff - g) : 0.0f;
    part[0] = fmaf(filt, filt, part[0]);
    const float den = fmaf(1.2f, u2, kk);
    const float d   = -filt * __builtin_amdgcn_rcpf(den);
    du[e] = d;
    const float d2  = d * d;
    const float Bc  = 1.2f * uu * d2;
    const float Cc  = 0.4f * d2 * d;
#pragma unroll
    for (int t = 0; t < 6; ++t) {
      const float a  = AL[t];
      const float cr = fmaf(a, fmaf(a, fmaf(-Cc, a, -Bc), filt), filt);
      part[1 + t] = fmaf(cr, cr, part[1 + t]);
    }
  }
}

__device__ __forceinline__ float sum_pick_fb(float (*red)[8], int n, int b, int tid) {
  if (tid < FNBX) {
#pragma unroll
    for (int j = 0; j < 7; ++j)
      red[tid][j] = __hip_atomic_load(&g_part[n][b][tid][j], __ATOMIC_RELAXED,
                                      __HIP_MEMORY_SCOPE_AGENT);
  }
  __syncthreads();
#pragma unroll
  for (int s = 64; s >= 1; s >>= 1) {
    if (tid < s && tid + s < FNBX) {
#pragma unroll
      for (int j = 0; j < 7; ++j) red[tid][j] += red[tid + s][j];
    }
    __syncthreads();
  }
  const float initn = sqrtf(red[0][0]);
  const float AL[6] = {1.0f, 0.5f, 0.25f, 0.125f, 0.0625f, 0.05f};
  float ab = 0.05f;
  bool found = false;
#pragma unroll
  for (int t = 0; t < 6; ++t) {
    const float nt = sqrtf(red[0][1 + t]);
    if (!found && nt < initn) { ab = AL[t]; found = true; }
  }
  __syncthreads();
  return ab;
}

template<bool BF>
__device__ __forceinline__ void load_state_fb(const void* U0, const void* F,
                                              const void* KD, int n, long long gb,
                                              int d0, float* u, float* f, float* kv) {
  if (n == 0) load16<BF>(U0, gb, u);
  else {
#pragma unroll
    for (int i = 0; i < 4; ++i) {
      float4 q = *(const float4*)(g_UW + gb + 4*i);
      u[4*i] = q.x; u[4*i+1] = q.y; u[4*i+2] = q.z; u[4*i+3] = q.w;
    }
  }
  load16<BF>(F, gb, f);
  load16<BF>(KD, d0, kv);
}

__global__ void __launch_bounds__(FTPB) k_part_fb(const void* __restrict__ F,
                                                  const void* __restrict__ U0,
                                                  const void* __restrict__ KD,
                                                  const int* __restrict__ FIX, int n) {
  const int tid = threadIdx.x, bid = blockIdx.x;
  const int b = bid / FNBX, bx = bid - b * FNBX;
  const int d0 = bx * FEPB + tid * FEPT;
  const bool act = (d0 < DOF);
  const long long gb = (long long)b * DOF + d0;
  const bool bf = probe_bf(KD);
  __shared__ u32   mw[FEPB / 32];
  __shared__ float sred[FTPB / 64][8];
  const u32 mbits = build_mask_fb(FIX, bx * FEPB, tid, mw);
  float u[FEPT], f[FEPT], kv[FEPT], du[FEPT];
  if (act) {
    if (bf) load_state_fb<true >(U0, F, KD, n, gb, d0, u, f, kv);
    else    load_state_fb<false>(U0, F, KD, n, gb, d0, u, f, kv);
  }
  float part[7];
  compute_partials7(act, u, f, kv, du, mbits, part);
  const int lane = tid & 63, wid = tid >> 6;
#pragma unroll
  for (int j = 0; j < 7; ++j) {
    float v = part[j];
#pragma unroll
    for (int o = 32; o > 0; o >>= 1) v += __shfl_down(v, o, 64);
    if (lane == 0) sred[wid][j] = v;
  }
  __syncthreads();
  if (tid < 7)
    g_part[n][b][bx][tid] = sred[0][tid] + sred[1][tid] + sred[2][tid] + sred[3][tid];
}

__global__ void __launch_bounds__(FTPB) k_upd_fb(const void* __restrict__ F,
                                                 const void* __restrict__ U0,
                                                 const void* __restrict__ KD,
                                                 const int* __restrict__ FIX,
                                                 void* __restrict__ OUT, int n, int last) {
  const int tid = threadIdx.x, bid = blockIdx.x;
  const int b = bid / FNBX, bx = bid - b * FNBX;
  const int d0 = bx * FEPB + tid * FEPT;
  const bool act = (d0 < DOF);
  const long long gb = (long long)b * DOF + d0;
  const bool bf = probe_bf(KD);
  __shared__ u32   mw[FEPB / 32];
  __shared__ float red[80][8];
  const u32 mbits = build_mask_fb(FIX, bx * FEPB, tid, mw);
  const float ab = sum_pick_fb(red, n, b, tid);
  if (!act) return;
  float u[FEPT], f[FEPT], kv[FEPT], du[FEPT];
  if (bf) load_state_fb<true >(U0, F, KD, n, gb, d0, u, f, kv);
  else    load_state_fb<false>(U0, F, KD, n, gb, d0, u, f, kv);
  float part[7];
  compute_partials7(act, u, f, kv, du, mbits, part);   // recompute du
#pragma unroll
  for (int e = 0; e < FEPT; ++e) u[e] = fmaf(ab, du[e], u[e]);
#pragma unroll
  for (int i = 0; i < 4; ++i)
    *(float4*)(g_UW + gb + 4*i) = make_float4(u[4*i], u[4*i+1], u[4*i+2], u[4*i+3]);
  if (last) {
    if (bf) store16<true >(OUT, gb, u);
    else    store16<false>(OUT, gb, u);
  }
}

extern "C" void kernel_launch(void* const* d_in, const int* in_sizes, int n_in,
                              void* d_out, int out_size, void* d_ws, size_t ws_size,
                              hipStream_t stream) {
  const void* F   = d_in[0];               // external_forces [B, DOF]
  const void* U0  = d_in[1];               // u0              [B, DOF]
  const void* KD  = d_in[2];               // k_diag          [DOF]
  const int*  FIX = (const int*)d_in[3];   // fixed_dofs      [NFIX] int32
  void* OUT = d_out;

  void* args[] = {(void*)&F, (void*)&U0, (void*)&KD, (void*)&FIX, (void*)&OUT};
  hipError_t e = hipLaunchCooperativeKernel((void*)k_coop, dim3(CGRID), dim3(CTPB),
                                            args, 0, stream);
  if (e != hipSuccess) {
    (void)hipGetLastError();               // clear sticky error, take fallback
    for (int n = 0; n < NEWTON; ++n) {
      k_part_fb<<<FGRID, FTPB, 0, stream>>>(F, U0, KD, FIX, n);
      k_upd_fb<<<FGRID, FTPB, 0, stream>>>(F, U0, KD, FIX, d_out, n,
                                           (n == NEWTON - 1) ? 1 : 0);
    }
  }
}

// Round 5
// 98.225 us; speedup vs baseline: 1.5643x; 1.2400x over previous
//
#include <hip/hip_runtime.h>

typedef unsigned short u16;
typedef unsigned int   u32;
typedef unsigned long long u64;
typedef long long i64;

constexpr int DOF    = 300000;
constexpr int NB     = 8;
constexpr int NFIX   = 3000;
constexpr int NEWTON = 6;

// ---- config: 240 blocks x 512 thr x 20 elem, 1 block/CU, balanced ----
// Coalesced chunking: thread owns CCH float4-chunks at lane-consecutive
// positions (c*CTPB+tid)*4 -> every global load/store is 64x16B contiguous.
constexpr int CTPB  = 512;
constexpr int CCH   = 5;                           // float4 chunks / thread
constexpr int CEPT  = CCH * 4;                     // 20
constexpr int CEPB  = CTPB * CEPT;                 // 10240
constexpr int CNBX  = (DOF + CEPB - 1) / CEPB;     // 30 blocks per batch
constexpr int CGRID = CNBX * NB;                   // 240
constexpr int WPB   = CTPB / 64;                   // 8 waves/block
constexpr int ARR   = WPB * CNBX;                  // 240 adds per acc line
constexpr int NLINES = NEWTON * NB * 6;            // 288 acc lines per bank

// Speculated line-search outcome (HW-verified in round 2: pick==5 passes
// verification on every call). The reference solves A*du = -filtered
// (du = -H^-1 r, ASCENT direction): no trial alpha reduces the norm ->
// any_imp=False -> alpha=ALPHA_MIN=0.05 (pick_idx==5) every round.
constexpr int   SPEC_PICK  = 5;
constexpr float SPEC_ALPHA = 0.05f;

// acc line: u64 fixed-point sum (scale 2^20, per-add bias 2^44). k_spec
// streams 240 per-wave adds per line (no count byte needed: the DISPATCH
// BOUNDARY between k_spec and k_verify is the synchronization). Worst-case
// clamped magnitude 240*(2^44+2^43) < 2^56. Integer adds are order-
// independent -> every k_verify block decodes identical values ->
// deterministic grid-uniform verdict. g_facc lines (fallback only) carry an
// arrival count in the top byte for intra-kernel polling. Parity-banked
// across calls; current call's banks were zeroed by the previous call's
// k_verify (stream-serialized).
struct alignas(64) PadU64 { u64 v; u64 pad[7]; };
__device__ PadU64 g_acc [2][NEWTON][NB][6];
__device__ PadU64 g_facc[2][NEWTON][NB][6];
__device__ PadU64 g_done[2];                       // parity-banked finish count
__device__ u32    g_call;                          // bumped after ALL blocks done

constexpr u64   CNT_ONE  = 1ull << 56;
constexpr u64   SUM_MASK = CNT_ONE - 1ull;
constexpr i64   ABIAS    = 1ll << 44;
constexpr float FXS      = 1048576.0f;             // 2^20
constexpr float FXS_INV  = 9.5367431640625e-07f;   // 2^-20

__device__ __forceinline__ u16 f2b(float f) {      // f32 -> bf16 RNE
  u32 x = __float_as_uint(f);
  u32 r = x + 0x7fffu + ((x >> 16) & 1u);
  return (u16)(r >> 16);
}

// NaN-safe clamp + fixed-point encode. Clamp at 8e6 never binds on the
// normal path (per-wave partials ~1e3); if the speculative trajectory
// diverges it keeps the sum below 2^56, and the bad round is detected via
// the pick mismatch.
__device__ __forceinline__ u64 enc_sum(float s) {
  float sa = s;
  if (!(sa > -8.0e6f)) sa = -8.0e6f;
  if (sa > 8.0e6f)     sa = 8.0e6f;
  return (u64)((i64)(sa * FXS) + ABIAS);
}

__device__ __forceinline__ float dec_sum(u64 v) {
  return (float)((i64)(v & SUM_MASK) - (i64)ARR * ABIAS) * FXS_INV;
}

// Fallback-only: spin until line's arrival count == ARR, then decode.
__device__ __forceinline__ float poll_line(u64* p) {
  u64 v = __hip_atomic_load(p, __ATOMIC_RELAXED, __HIP_MEMORY_SCOPE_AGENT);
  while ((v >> 56) != (u64)ARR) {
    __builtin_amdgcn_s_sleep(8);
    v = __hip_atomic_load(p, __ATOMIC_RELAXED, __HIP_MEMORY_SCOPE_AGENT);
  }
  return dec_sum(v);
}

// ---- 4-elem chunk load/store. f32: float4 (16B-aligned); bf16: uint2
// (8B-aligned). Lane-consecutive chunks -> fully coalesced. ----
template<bool BF>
__device__ __forceinline__ void load4(const void* p, long long eoff, float* dst) {
  if (BF) {
    const u16* b = (const u16*)p + eoff;
    uint2 a = *(const uint2*)b;
    dst[0] = __uint_as_float((a.x & 0xffffu) << 16);
    dst[1] = __uint_as_float(a.x & 0xffff0000u);
    dst[2] = __uint_as_float((a.y & 0xffffu) << 16);
    dst[3] = __uint_as_float(a.y & 0xffff0000u);
  } else {
    float4 v = *(const float4*)((const float*)p + eoff);
    dst[0] = v.x; dst[1] = v.y; dst[2] = v.z; dst[3] = v.w;
  }
}

template<bool BF>
__device__ __forceinline__ void store4(void* p, long long eoff, const float* s) {
  if (BF) {
    u16* b = (u16*)p + eoff;
    *(uint2*)b = make_uint2((u32)f2b(s[0]) | ((u32)f2b(s[1]) << 16),
                            (u32)f2b(s[2]) | ((u32)f2b(s[3]) << 16));
  } else {
    *(float4*)((float*)p + eoff) = make_float4(s[0], s[1], s[2], s[3]);
  }
}

// dtype probe: k_diag in [1,2). bf16 -> every u16 in [0x3F80,0x4000]; f32 even
// words are random mantissa halves (false-positive p ~ 2e-22 over 8 words).
__device__ __forceinline__ bool probe_bf(const void* KD) {
  const u16* k = (const u16*)KD;
  bool bf = true;
#pragma unroll
  for (int i = 0; i < 8; ++i) {
    u16 v = k[2*i];
    bf = bf && (v >= 0x3F80u && v <= 0x4000u);
  }
  return bf;
}

// Gram-form partials: cr(a) = filt*(1+a) - P*a^2 - Q*a^3, P=1.2*u*d^2,
// Q=0.4*d^3, d = -filt/den (exact cubic since den*d = -filt). sum cr(a)^2
// is a quadratic form in (filt,P,Q) -> 6 sums cover init-norm^2 and all 6
// trial norms. Fixed dofs: filt=0 -> d=P=Q=0. Inactive chunks are loaded
// with u=f=0, kv=1 -> filt=0 -> contribute nothing, du=0.
template<int NE>
__device__ __forceinline__ void compute_gram(const float* u, const float* f,
                                             const float* kv, float* du,
                                             u32 mbits, float* G) {
#pragma unroll
  for (int j = 0; j < 6; ++j) G[j] = 0.0f;
#pragma unroll
  for (int e = 0; e < NE; ++e) {
    const bool fr = ((mbits >> e) & 1u) == 0u;
    const float uu = u[e], ff = f[e], kk = kv[e];
    const float u2 = uu * uu;
    const float g    = fmaf(0.4f * u2, uu, kk * uu);
    const float filt = fr ? (ff - g) : 0.0f;
    const float den  = fmaf(1.2f, u2, kk);
    const float d    = -filt * __builtin_amdgcn_rcpf(den);
    du[e] = d;
    const float d2 = d * d;
    const float P  = (1.2f * uu) * d2;
    const float Q  = (0.4f * d2) * d;
    G[0] = fmaf(filt, filt, G[0]);
    G[1] = fmaf(filt, P,    G[1]);
    G[2] = fmaf(filt, Q,    G[2]);
    G[3] = fmaf(P,    P,    G[3]);
    G[4] = fmaf(P,    Q,    G[4]);
    G[5] = fmaf(Q,    Q,    G[5]);
  }
}

// alpha pick from 6 Gram sums (compare squared; fallback idx 5 == 0.05)
__device__ __forceinline__ int pick_idx(const float* G) {
  const float AL[6] = {1.0f, 0.5f, 0.25f, 0.125f, 0.0625f, 0.05f};
  int idx = 5;
  bool found = false;
#pragma unroll
  for (int t = 0; t < 6; ++t) {
    const float a = AL[t], s = 1.0f + a, a2 = a * a;
    const float n2 = s * s * G[0] - 2.0f * s * a2 * G[1] - 2.0f * s * a2 * a * G[2]
                   + a2 * a2 * G[3] + 2.0f * a2 * a2 * a * G[4]
                   + a2 * a2 * a2 * G[5];
    if (!found && n2 < G[0]) { idx = t; found = true; }
  }
  return idx;
}

// block-local fixed-dof bitmask over this block's CEPB-dof window; returns
// this thread's 20 mask bits (5 nibbles, 4-aligned -> never span words).
__device__ __forceinline__ u32 build_mask(const int* __restrict__ FIX,
                                          int blk_base, int tid, u32* mw) {
  for (int i = tid; i < CEPB / 32; i += CTPB) mw[i] = 0u;
  __syncthreads();
  for (int i = tid; i < NFIX; i += CTPB) {
    const int d = FIX[i] - blk_base;
    if (d >= 0 && d < CEPB) atomicOr(&mw[d >> 5], 1u << (d & 31));
  }
  __syncthreads();
  u32 mbits = 0u;
#pragma unroll
  for (int c = 0; c < CCH; ++c) {
    const int pos = (c * CTPB + tid) * 4;
    mbits |= ((mw[pos >> 5] >> (pos & 31)) & 0xFu) << (4 * c);
  }
  return mbits;
}

// ===================== k_spec: pure streaming, zero waits =====================
// Load -> 6 speculative Newton rounds (alpha=SPEC_ALPHA) -> store OUT.
// Each wave butterfly-reduces its 6 Gram partials and fires ONE per-wave
// fixed-point atomic add per line (fire-and-forget). No barriers per round,
// no polls, no cross-block communication: the dispatch boundary to k_verify
// is the grid synchronization. Regular launch; deadlock-impossible.
__global__ void __launch_bounds__(CTPB, 2) k_spec(const void* __restrict__ F,
                                                  const void* __restrict__ U0,
                                                  const void* __restrict__ KD,
                                                  const int* __restrict__ FIX,
                                                  void* __restrict__ OUT) {
  const int tid = threadIdx.x, bid = blockIdx.x;
  const int b = bid / CNBX, bx = bid - b * CNBX;
  const int blk_base = bx * CEPB;
  const bool bf = probe_bf(KD);
  __shared__ u32 mw[CEPB / 32];

  const u32 call = __hip_atomic_load(&g_call, __ATOMIC_RELAXED,
                                     __HIP_MEMORY_SCOPE_AGENT);
  const int par  = (int)(call & 1u);

  // chunk geometry + coalesced prefetch (overlaps with mask build)
  int  cpos[CCH];
  bool okc[CCH];
  float u[CEPT], f[CEPT], kv[CEPT], du[CEPT];
#pragma unroll
  for (int c = 0; c < CCH; ++c) {
    cpos[c] = (c * CTPB + tid) * 4;
    okc[c]  = (blk_base + cpos[c] + 4 <= DOF);
    const long long ge = (long long)b * DOF + blk_base + cpos[c];
    const long long ke = blk_base + cpos[c];
    if (okc[c]) {
      if (bf) { load4<true >(U0, ge, &u[4*c]); load4<true >(F, ge, &f[4*c]); load4<true >(KD, ke, &kv[4*c]); }
      else    { load4<false>(U0, ge, &u[4*c]); load4<false>(F, ge, &f[4*c]); load4<false>(KD, ke, &kv[4*c]); }
    } else {
#pragma unroll
      for (int j = 0; j < 4; ++j) { u[4*c+j] = 0.0f; f[4*c+j] = 0.0f; kv[4*c+j] = 1.0f; }
    }
  }

  const u32 mbits = build_mask(FIX, blk_base, tid, mw);
  const int lane = tid & 63;

  for (int n = 0; n < NEWTON; ++n) {
    float G[6];
    compute_gram<CEPT>(u, f, kv, du, mbits, G);
    // per-wave butterfly: every lane ends with the full wave sum of each G[j]
    float r[6];
#pragma unroll
    for (int j = 0; j < 6; ++j) {
      float v = G[j];
#pragma unroll
      for (int o = 32; o > 0; o >>= 1) v += __shfl_xor(v, o, 64);
      r[j] = v;
    }
    if (lane < 6) {                          // one atomic instr, 6 lanes
      const float s = lane == 0 ? r[0] : lane == 1 ? r[1] : lane == 2 ? r[2]
                    : lane == 3 ? r[3] : lane == 4 ? r[4] : r[5];
      (void)__hip_atomic_fetch_add(&g_acc[par][n][b][lane].v, enc_sum(s),
                                   __ATOMIC_RELAXED, __HIP_MEMORY_SCOPE_AGENT);
    }
#pragma unroll
    for (int e = 0; e < CEPT; ++e) u[e] = fmaf(SPEC_ALPHA, du[e], u[e]);
  }

  // speculative store; k_verify overwrites only on (never-observed) mismatch
#pragma unroll
  for (int c = 0; c < CCH; ++c) {
    if (okc[c]) {
      const long long ge = (long long)b * DOF + blk_base + cpos[c];
      if (bf) store4<true >(OUT, ge, &u[4*c]);
      else    store4<false>(OUT, ge, &u[4*c]);
    }
  }
}

// ===================== k_verify: boundary-synced verdict =====================
// The dispatch boundary guarantees all k_spec adds are complete and visible.
// Fast path (speculation holds): one wave reads this batch's 36 lines,
// verdict, zero other-parity banks, epilogue. No waits of any kind.
// Mismatch path: in-kernel poll-synced exact rerun (240 blocks @ 1/CU are
// trivially co-resident; this path has never triggered on HW).
__global__ void __launch_bounds__(CTPB, 2) k_verify(const void* __restrict__ F,
                                                    const void* __restrict__ U0,
                                                    const void* __restrict__ KD,
                                                    const int* __restrict__ FIX,
                                                    void* __restrict__ OUT) {
  const int tid = threadIdx.x, bid = blockIdx.x;
  const int b = bid / CNBX, bx = bid - b * CNBX;
  const int blk_base = bx * CEPB;
  const float ALTAB[6] = {1.0f, 0.5f, 0.25f, 0.125f, 0.0625f, 0.05f};

  __shared__ u32   mw[CEPB / 32];
  __shared__ float sG[NEWTON * 6];
  __shared__ float gG[8];
  __shared__ u32   sflag;

  const u32 call = __hip_atomic_load(&g_call, __ATOMIC_RELAXED,
                                     __HIP_MEMORY_SCOPE_AGENT);
  const int par  = (int)(call & 1u);

  // read this batch's 36 exact sums (identical integers in every block)
  if (tid < NEWTON * 6) {
    const int n = tid / 6, j = tid - n * 6;
    const u64 v = __hip_atomic_load(&g_acc[par][n][b][j].v, __ATOMIC_RELAXED,
                                    __HIP_MEMORY_SCOPE_AGENT);
    sG[tid] = dec_sum(v);
  }

  // zero the OTHER parity's banks (their last user, call-1, fully retired
  // at the dispatch boundary): 2*288 lines / 240 blocks = <=3 stores/block.
  if (tid == 0) {
    for (int L = bid; L < 2 * NLINES; L += CGRID) {
      const int s  = L / NLINES;
      const int r  = L % NLINES;
      const int n2 = r / (NB * 6), rr = r % (NB * 6);
      u64* p = s ? &g_facc[par ^ 1][n2][rr / 6][rr % 6].v
                 : &g_acc [par ^ 1][n2][rr / 6][rr % 6].v;
      __hip_atomic_store(p, 0ull, __ATOMIC_RELAXED, __HIP_MEMORY_SCOPE_AGENT);
    }
    if (bid == 0)
      __hip_atomic_store(&g_done[par ^ 1].v, 0ull,
                         __ATOMIC_RELAXED, __HIP_MEMORY_SCOPE_AGENT);
  }
  __syncthreads();

  if (tid == 0) {
    u32 okf = 1u;
#pragma unroll
    for (int n = 0; n < NEWTON; ++n)
      okf &= (pick_idx(&sG[6 * n]) == SPEC_PICK) ? 1u : 0u;
    sflag = okf;
  }
  __syncthreads();

  if (!sflag) {
    // ---------- exact synced rerun (rare path; poll-synced) ----------
    const bool bf = probe_bf(KD);
    int  cpos[CCH];
    bool okc[CCH];
    float u[CEPT], f[CEPT], kv[CEPT], du[CEPT];
#pragma unroll
    for (int c = 0; c < CCH; ++c) {
      cpos[c] = (c * CTPB + tid) * 4;
      okc[c]  = (blk_base + cpos[c] + 4 <= DOF);
      const long long ge = (long long)b * DOF + blk_base + cpos[c];
      const long long ke = blk_base + cpos[c];
      if (okc[c]) {
        if (bf) { load4<true >(U0, ge, &u[4*c]); load4<true >(F, ge, &f[4*c]); load4<true >(KD, ke, &kv[4*c]); }
        else    { load4<false>(U0, ge, &u[4*c]); load4<false>(F, ge, &f[4*c]); load4<false>(KD, ke, &kv[4*c]); }
      } else {
#pragma unroll
        for (int j = 0; j < 4; ++j) { u[4*c+j] = 0.0f; f[4*c+j] = 0.0f; kv[4*c+j] = 1.0f; }
      }
    }
    const u32 mbits = build_mask(FIX, blk_base, tid, mw);
    const int lane = tid & 63;

    for (int n = 0; n < NEWTON; ++n) {
      float G[6];
      compute_gram<CEPT>(u, f, kv, du, mbits, G);
      float r[6];
#pragma unroll
      for (int j = 0; j < 6; ++j) {
        float v = G[j];
#pragma unroll
        for (int o = 32; o > 0; o >>= 1) v += __shfl_xor(v, o, 64);
        r[j] = v;
      }
      if (lane < 6) {                        // arrival-counted add
        const float s = lane == 0 ? r[0] : lane == 1 ? r[1] : lane == 2 ? r[2]
                      : lane == 3 ? r[3] : lane == 4 ? r[4] : r[5];
        (void)__hip_atomic_fetch_add(&g_facc[par][n][b][lane].v,
                                     CNT_ONE | enc_sum(s), __ATOMIC_RELAXED,
                                     __HIP_MEMORY_SCOPE_AGENT);
      }
      if (tid < 6) gG[tid] = poll_line(&g_facc[par][n][b][tid].v);
      __syncthreads();
      float GG[6];
#pragma unroll
      for (int j = 0; j < 6; ++j) GG[j] = gG[j];
      const float ab = ALTAB[pick_idx(GG)];
#pragma unroll
      for (int e = 0; e < CEPT; ++e) u[e] = fmaf(ab, du[e], u[e]);
      __syncthreads();                       // gG WAR vs next round
    }
#pragma unroll
    for (int c = 0; c < CCH; ++c) {
      if (okc[c]) {
        const long long ge = (long long)b * DOF + blk_base + cpos[c];
        if (bf) store4<true >(OUT, ge, &u[4*c]);
        else    store4<false>(OUT, ge, &u[4*c]);
      }
    }
  }

  // g_call bump gated on ALL blocks done (every block has already read
  // g_call by the time the last g_done increment lands -> no parity race).
  if (tid == 0) {
    const u64 old = __hip_atomic_fetch_add(&g_done[par].v, 1ull,
                                           __ATOMIC_RELAXED,
                                           __HIP_MEMORY_SCOPE_AGENT);
    if (old == (u64)(CGRID - 1))
      __hip_atomic_store(&g_call, call + 1u, __ATOMIC_RELAXED,
                         __HIP_MEMORY_SCOPE_AGENT);
  }
}

extern "C" void kernel_launch(void* const* d_in, const int* in_sizes, int n_in,
                              void* d_out, int out_size, void* d_ws, size_t ws_size,
                              hipStream_t stream) {
  const void* F   = d_in[0];               // external_forces [B, DOF]
  const void* U0  = d_in[1];               // u0              [B, DOF]
  const void* KD  = d_in[2];               // k_diag          [DOF]
  const int*  FIX = (const int*)d_in[3];   // fixed_dofs      [NFIX] int32
  void* OUT = d_out;

  k_spec  <<<CGRID, CTPB, 0, stream>>>(F, U0, KD, FIX, OUT);
  k_verify<<<CGRID, CTPB, 0, stream>>>(F, U0, KD, FIX, OUT);
}